// Round 2
// baseline (666.689 us; speedup 1.0000x reference)
//
#include <hip/hip_runtime.h>

typedef __attribute__((ext_vector_type(8))) short short8;
typedef __attribute__((ext_vector_type(4))) short short4v;
typedef __attribute__((ext_vector_type(4))) float f32x4;
typedef __attribute__((ext_vector_type(4))) unsigned short us4;

__device__ __forceinline__ unsigned short f2bf(float f) {
  unsigned u = __builtin_bit_cast(unsigned, f);
  u += 0x7FFFu + ((u >> 16) & 1u);
  return (unsigned short)(u >> 16);
}

__device__ __forceinline__ void gll16(const void* g, void* l) {
  __builtin_amdgcn_global_load_lds(
      (const __attribute__((address_space(1))) void*)g,
      (__attribute__((address_space(3))) void*)l, 16, 0, 0);
}

__device__ __forceinline__ f32x4 MFMA(short8 a, short8 b, f32x4 c) {
  return __builtin_amdgcn_mfma_f32_16x16x32_bf16(a, b, c, 0, 0, 0);
}

// ---------------- prep kernels ----------------

__global__ void conv_bf16(const float* __restrict__ in, unsigned short* __restrict__ out, int n4) {
  for (int i = blockIdx.x * blockDim.x + threadIdx.x; i < n4; i += gridDim.x * blockDim.x) {
    float4 v = ((const float4*)in)[i];
    us4 o;
    o[0] = f2bf(v.x); o[1] = f2bf(v.y); o[2] = f2bf(v.z); o[3] = f2bf(v.w);
    ((us4*)out)[i] = o;
  }
}

// in: fp32 [R][C] -> out: bf16 [C][R], scaled
__global__ void tconv(const float* __restrict__ in, unsigned short* __restrict__ out,
                      int R, int C, float scale) {
  __shared__ float tile[32][33];
  int bx = blockIdx.x, by = blockIdx.y;
  int tx = threadIdx.x, ty = threadIdx.y;
#pragma unroll
  for (int i = 0; i < 4; ++i)
    tile[ty + i * 8][tx] = in[(long)(by * 32 + ty + i * 8) * C + bx * 32 + tx];
  __syncthreads();
#pragma unroll
  for (int i = 0; i < 4; ++i)
    out[(long)(bx * 32 + ty + i * 8) * R + by * 32 + tx] = f2bf(tile[tx][ty + i * 8] * scale);
}

// C[128][128] = A[128][64] @ B[64][128]   (fp32, tiny)
__global__ void fold_wc(const float* __restrict__ A, const float* __restrict__ Bm,
                        float* __restrict__ Cm) {
  int j = threadIdx.x;  // 128
  int m = blockIdx.x;   // 128
  float acc = 0.f;
#pragma unroll
  for (int l = 0; l < 64; ++l) acc += A[m * 64 + l] * Bm[l * 128 + j];
  Cm[m * 128 + j] = acc;
}

// We[k][h*128+j] = sum_m W[k][h*128+m] * Wc[m][j]
__global__ void make_eff(const float* __restrict__ W, const float* __restrict__ Wc,
                         float* __restrict__ We) {
  int j = threadIdx.x;  // 128
  int k = blockIdx.x;   // 2048
  int h = blockIdx.y;   // 4
  const float* wrow = W + (long)k * 512 + h * 128;
  float acc = 0.f;
#pragma unroll 8
  for (int m = 0; m < 128; ++m) acc += wrow[m] * Wc[m * 128 + j];
  We[(long)k * 512 + h * 128 + j] = acc;
}

// ---------------- GEMM: C[M][N] = A[M][K] @ BT[N][K]^T  (bf16 in, m97 structure) ----------------
// EPI 0: bf16 C row-major; 1: bf16 C transposed ([N][M]); 2: f32 C row-major
template <int EPI>
__global__ __launch_bounds__(256, 2) void gemm_bt(const unsigned short* __restrict__ A,
                                                  const unsigned short* __restrict__ BT,
                                                  void* __restrict__ Cout, int M, int N, int K) {
  __shared__ unsigned short As[128 * 32];
  __shared__ unsigned short Bs[128 * 32];
  const int tid = threadIdx.x;
  const int lane = tid & 63, w = tid >> 6;
  const int wr = w >> 1, wc = w & 1;
  const int c = lane & 15, hi = lane >> 4;
  const int nbn = N >> 7;
  // XCD-aware bijective swizzle (grid % 8 == 0 for all our launches)
  int bid = blockIdx.x;
  bid = (bid & 7) * (gridDim.x >> 3) + (bid >> 3);
  const int bm = bid / nbn, bn = bid % nbn;
  const int row0 = bm << 7, col0 = bn << 7;

  const unsigned short* ga = A + (long)(row0 + (tid >> 2)) * K + ((tid & 3) << 3);
  const unsigned short* gb = BT + (long)(col0 + (tid >> 2)) * K + ((tid & 3) << 3);
  unsigned short* la = As + tid * 8;
  unsigned short* lb = Bs + tid * 8;
  const long sA = (long)64 * K;

  f32x4 acc[4][4] = {};

  for (int k0 = 0; k0 < K; k0 += 32) {
    __syncthreads();
    gll16(ga + k0, la);
    gll16(ga + sA + k0, la + 2048);
    gll16(gb + k0, lb);
    gll16(gb + sA + k0, lb + 2048);
    __syncthreads();
    short8 a[4], b[4];
#pragma unroll
    for (int m = 0; m < 4; ++m)
      a[m] = *(const short8*)&As[(wr * 64 + m * 16 + c) * 32 + hi * 8];
#pragma unroll
    for (int n = 0; n < 4; ++n)
      b[n] = *(const short8*)&Bs[(wc * 64 + n * 16 + c) * 32 + hi * 8];
#pragma unroll
    for (int m = 0; m < 4; ++m)
#pragma unroll
      for (int n = 0; n < 4; ++n) acc[m][n] = MFMA(a[m], b[n], acc[m][n]);
  }

  if (EPI == 0) {
    unsigned short* C = (unsigned short*)Cout;
#pragma unroll
    for (int m = 0; m < 4; ++m) {
      int r0 = row0 + wr * 64 + m * 16 + hi * 4;
#pragma unroll
      for (int n = 0; n < 4; ++n) {
        int cc = col0 + wc * 64 + n * 16 + c;
#pragma unroll
        for (int j = 0; j < 4; ++j) C[(long)(r0 + j) * N + cc] = f2bf(acc[m][n][j]);
      }
    }
  } else if (EPI == 1) {
    unsigned short* C = (unsigned short*)Cout;  // [N][M]
#pragma unroll
    for (int m = 0; m < 4; ++m) {
      int r0 = row0 + wr * 64 + m * 16 + hi * 4;
#pragma unroll
      for (int n = 0; n < 4; ++n) {
        int cc = col0 + wc * 64 + n * 16 + c;
        us4 v;
#pragma unroll
        for (int j = 0; j < 4; ++j) v[j] = f2bf(acc[m][n][j]);
        *(us4*)&C[(long)cc * M + r0] = v;
      }
    }
  } else {
    float* C = (float*)Cout;
#pragma unroll
    for (int m = 0; m < 4; ++m) {
      int r0 = row0 + wr * 64 + m * 16 + hi * 4;
#pragma unroll
      for (int n = 0; n < 4; ++n) {
        int cc = col0 + wc * 64 + n * 16 + c;
#pragma unroll
        for (int j = 0; j < 4; ++j) C[(long)(r0 + j) * N + cc] = acc[m][n][j];
      }
    }
  }
}

// ---------------- attention ----------------
// Q: [8192][2048] bf16 (pre-scaled by log2e/sqrt(128) -> base-2 softmax);
// Kr: [8192][512]; VT: [512][8192]; out CTX: [8192][2048] bf16.
// grid (T/64=32, H=16, B=4), 256 threads (4 waves x 16 q-rows).
// Double-buffered K/V staging (one barrier/tile), defer-max, conflict-free Ps (stride 68).
__global__ __launch_bounds__(256, 2) void attn_kernel(const unsigned short* __restrict__ Q,
                                                      const unsigned short* __restrict__ Kr,
                                                      const unsigned short* __restrict__ VT,
                                                      unsigned short* __restrict__ CTX) {
  const int qt = blockIdx.x, h = blockIdx.y, b = blockIdx.z;
  const int kvh = h >> 2;
  const int tid = threadIdx.x, lane = tid & 63, w = tid >> 6;
  const int c = lane & 15, hi = lane >> 4;

  __shared__ unsigned short Ks[2][64 * 128];   // [key][d], XOR-swizzled
  __shared__ unsigned short Vs[2][128 * 64];   // [d][key], XOR-swizzled
  __shared__ unsigned short Ps[4][16 * 68];    // per-wave P, stride 68 (conflict-free)

  const long qrow = (long)(b * 2048 + qt * 64 + w * 16 + c);
  short8 aq[4];
#pragma unroll
  for (int kk = 0; kk < 4; ++kk)
    aq[kk] = *(const short8*)&Q[qrow * 2048 + h * 128 + kk * 32 + hi * 8];

  f32x4 acc[8] = {};
  float mrow[4] = {-1e30f, -1e30f, -1e30f, -1e30f};
  float lrow[4] = {0.f, 0.f, 0.f, 0.f};

  const unsigned short* kbase = Kr + (long)b * 2048 * 512 + kvh * 128;
  const unsigned short* vbase = VT + (long)kvh * 128 * 8192 + b * 2048;

  // per-thread staging offsets (pre-swizzled global source, linear LDS dest)
  int kpo[4], vpo[4];
  long kgo[4], vgo[4];
#pragma unroll
  for (int i = 0; i < 4; ++i) {
    int p = i * 4096 + tid * 16;
    int key = p >> 8;
    int d0 = ((p & 255) ^ ((key & 7) << 4)) >> 1;
    kpo[i] = p;
    kgo[i] = (long)key * 512 + d0;
    int d = p >> 7;
    int key0 = ((p & 127) ^ ((d & 7) << 4)) >> 1;
    vpo[i] = p;
    vgo[i] = (long)d * 8192 + key0;
  }

  // prologue: stage tile 0 into buffer 0
#pragma unroll
  for (int i = 0; i < 4; ++i) gll16(kbase + kgo[i], (char*)Ks[0] + kpo[i]);
#pragma unroll
  for (int i = 0; i < 4; ++i) gll16(vbase + vgo[i], (char*)Vs[0] + vpo[i]);
  __syncthreads();

  int cur = 0;
  for (int t = 0; t < 32; ++t) {
    // issue next tile's loads into the other buffer (they fly under compute)
    if (t < 31) {
      const long ko = (long)(t + 1) * 64 * 512;
      const int vo = (t + 1) * 64;
#pragma unroll
      for (int i = 0; i < 4; ++i) gll16(kbase + ko + kgo[i], (char*)Ks[cur ^ 1] + kpo[i]);
#pragma unroll
      for (int i = 0; i < 4; ++i) gll16(vbase + vo + vgo[i], (char*)Vs[cur ^ 1] + vpo[i]);
    }

    const char* ks = (const char*)Ks[cur];
    const char* vs = (const char*)Vs[cur];

    // S = Q K^T  (16 q-rows x 64 keys per wave)
    f32x4 s[4] = {};
#pragma unroll
    for (int n = 0; n < 4; ++n) {
      int r = n * 16 + c;
#pragma unroll
      for (int kk = 0; kk < 4; ++kk) {
        int lb = r * 256 + kk * 64 + hi * 16;
        int sb = lb ^ ((r & 7) << 4);
        short8 bk = *(const short8*)(ks + sb);
        s[n] = MFMA(aq[kk], bk, s[n]);
      }
    }

    // online softmax in base-2, defer-max (THR = 11 in log2 units ~ 7.6 nats)
    float pv[4][4];
#pragma unroll
    for (int j = 0; j < 4; ++j) {
      float tmax = fmaxf(fmaxf(s[0][j], s[1][j]), fmaxf(s[2][j], s[3][j]));
      tmax = fmaxf(tmax, __shfl_xor(tmax, 1));
      tmax = fmaxf(tmax, __shfl_xor(tmax, 2));
      tmax = fmaxf(tmax, __shfl_xor(tmax, 4));
      tmax = fmaxf(tmax, __shfl_xor(tmax, 8));
      if (tmax > mrow[j] + 11.0f) {  // rescale only on significant max growth
        float sc = __builtin_amdgcn_exp2f(mrow[j] - tmax);
        mrow[j] = tmax;
        lrow[j] *= sc;
#pragma unroll
        for (int n8 = 0; n8 < 8; ++n8) acc[n8][j] *= sc;
      }
      float ps = 0.f;
#pragma unroll
      for (int n = 0; n < 4; ++n) {
        float e = __builtin_amdgcn_exp2f(s[n][j] - mrow[j]);
        pv[n][j] = e;
        ps += e;
      }
      ps += __shfl_xor(ps, 1);
      ps += __shfl_xor(ps, 2);
      ps += __shfl_xor(ps, 4);
      ps += __shfl_xor(ps, 8);
      lrow[j] += ps;
    }

    // P -> LDS (per-wave region, stride 68 elems = conflict-free scalar writes)
#pragma unroll
    for (int n = 0; n < 4; ++n)
#pragma unroll
      for (int j = 0; j < 4; ++j)
        Ps[w][(hi * 4 + j) * 68 + n * 16 + c] = f2bf(pv[n][j]);

    // re-read P in A-fragment layout (2x b64 per fragment; 136B row stride is 8B-aligned)
    short8 ap[2];
    {
      const char* pb = (const char*)(Ps[w]) + c * 136 + hi * 16;
#pragma unroll
      for (int kk = 0; kk < 2; ++kk) {
        short4v lo4 = *(const short4v*)(pb + kk * 64);
        short4v hi4 = *(const short4v*)(pb + kk * 64 + 8);
        short8 tt;
        tt[0] = lo4[0]; tt[1] = lo4[1]; tt[2] = lo4[2]; tt[3] = lo4[3];
        tt[4] = hi4[0]; tt[5] = hi4[1]; tt[6] = hi4[2]; tt[7] = hi4[3];
        ap[kk] = tt;
      }
    }

    // ctx += P V
#pragma unroll
    for (int n = 0; n < 8; ++n) {
      int r = n * 16 + c;
#pragma unroll
      for (int kk = 0; kk < 2; ++kk) {
        int lb = r * 128 + kk * 64 + hi * 16;
        int sb = lb ^ ((r & 7) << 4);
        short8 bv = *(const short8*)(vs + sb);
        acc[n] = MFMA(ap[kk], bv, acc[n]);
      }
    }

    __syncthreads();  // drains this iter's staging loads; publishes buf cur^1
    cur ^= 1;
  }

#pragma unroll
  for (int j = 0; j < 4; ++j) {
    float inv = 1.0f / lrow[j];
    long r = (long)(b * 2048 + qt * 64 + w * 16 + hi * 4 + j);
#pragma unroll
    for (int n = 0; n < 8; ++n)
      CTX[r * 2048 + h * 128 + n * 16 + c] = f2bf(acc[n][j] * inv);
  }
}

// ---------------- launch ----------------

extern "C" void kernel_launch(void* const* d_in, const int* in_sizes, int n_in, void* d_out,
                              int out_size, void* d_ws, size_t ws_size, hipStream_t stream) {
  (void)in_sizes; (void)n_in; (void)out_size; (void)ws_size;
  const float* x    = (const float*)d_in[0];
  const float* W_q  = (const float*)d_in[1];
  const float* W_k  = (const float*)d_in[2];
  const float* W_v  = (const float*)d_in[3];
  const float* Wk2l = (const float*)d_in[4];
  const float* Wv2l = (const float*)d_in[5];
  const float* Wkfl = (const float*)d_in[6];
  const float* Wvfl = (const float*)d_in[7];
  const float* W_o  = (const float*)d_in[8];
  float* out = (float*)d_out;

  char* ws = (char*)d_ws;
  unsigned short* Xb   = (unsigned short*)(ws + 0);          // 32 MiB (reused as CTXb)
  unsigned short* Qb   = (unsigned short*)(ws + 33554432);   // 32 MiB
  unsigned short* KRb  = (unsigned short*)(ws + 67108864);   // 8 MiB
  unsigned short* VTb  = (unsigned short*)(ws + 75497472);   // 8 MiB
  unsigned short* WqT  = (unsigned short*)(ws + 83886080);   // 8 MiB
  unsigned short* WoT  = (unsigned short*)(ws + 92274688);   // 8 MiB
  unsigned short* WkeT = (unsigned short*)(ws + 100663296);  // 2 MiB
  unsigned short* WveT = (unsigned short*)(ws + 102760448);  // 2 MiB
  float* Wkc    = (float*)(ws + 104857600);                  // 64 KiB
  float* Wvc    = (float*)(ws + 104923136);                  // 64 KiB
  float* Wstage = (float*)(ws + 104988672);                  // 4 MiB
  unsigned short* CTXb = Xb;

  // dtype conversion + weight folding (W_q scale includes 1/sqrt(Dh) AND log2e for base-2 softmax)
  conv_bf16<<<2048, 256, 0, stream>>>(x, Xb, 16777216 / 4);
  tconv<<<dim3(64, 64), dim3(32, 8), 0, stream>>>(W_q, WqT, 2048, 2048,
                                                  (float)(0.088388347648318447 * 1.4426950408889634));
  tconv<<<dim3(64, 64), dim3(32, 8), 0, stream>>>(W_o, WoT, 2048, 2048, 1.0f);
  fold_wc<<<128, 128, 0, stream>>>(Wk2l, Wkfl, Wkc);
  fold_wc<<<128, 128, 0, stream>>>(Wv2l, Wvfl, Wvc);
  make_eff<<<dim3(2048, 4), 128, 0, stream>>>(W_k, Wkc, Wstage);
  tconv<<<dim3(16, 64), dim3(32, 8), 0, stream>>>(Wstage, WkeT, 2048, 512, 1.0f);
  make_eff<<<dim3(2048, 4), 128, 0, stream>>>(W_v, Wvc, Wstage);
  tconv<<<dim3(16, 64), dim3(32, 8), 0, stream>>>(Wstage, WveT, 2048, 512, 1.0f);

  // projections
  gemm_bt<0><<<1024, 256, 0, stream>>>(Xb, WqT, Qb, 8192, 2048, 2048);
  gemm_bt<0><<<256, 256, 0, stream>>>(Xb, WkeT, KRb, 8192, 512, 2048);
  gemm_bt<1><<<256, 256, 0, stream>>>(Xb, WveT, VTb, 8192, 512, 2048);  // V stored transposed

  // attention
  attn_kernel<<<dim3(32, 16, 4), 256, 0, stream>>>(Qb, KRb, VTb, CTXb);

  // output projection -> fp32 d_out
  gemm_bt<2><<<1024, 256, 0, stream>>>(CTXb, WoT, out, 8192, 2048, 2048);
}

// Round 3
// 657.815 us; speedup vs baseline: 1.0135x; 1.0135x over previous
//
#include <hip/hip_runtime.h>

typedef __attribute__((ext_vector_type(8))) short short8;
typedef __attribute__((ext_vector_type(4))) short short4v;
typedef __attribute__((ext_vector_type(4))) float f32x4;
typedef __attribute__((ext_vector_type(4))) unsigned short us4;

__device__ __forceinline__ unsigned short f2bf(float f) {
  unsigned u = __builtin_bit_cast(unsigned, f);
  u += 0x7FFFu + ((u >> 16) & 1u);
  return (unsigned short)(u >> 16);
}

__device__ __forceinline__ void gll16(const void* g, void* l) {
  __builtin_amdgcn_global_load_lds(
      (const __attribute__((address_space(1))) void*)g,
      (__attribute__((address_space(3))) void*)l, 16, 0, 0);
}

__device__ __forceinline__ f32x4 MFMA(short8 a, short8 b, f32x4 c) {
  return __builtin_amdgcn_mfma_f32_16x16x32_bf16(a, b, c, 0, 0, 0);
}

// ---------------- prep kernels ----------------

__global__ void conv_bf16(const float* __restrict__ in, unsigned short* __restrict__ out, int n4) {
  for (int i = blockIdx.x * blockDim.x + threadIdx.x; i < n4; i += gridDim.x * blockDim.x) {
    float4 v = ((const float4*)in)[i];
    us4 o;
    o[0] = f2bf(v.x); o[1] = f2bf(v.y); o[2] = f2bf(v.z); o[3] = f2bf(v.w);
    ((us4*)out)[i] = o;
  }
}

// in: fp32 [R][C] -> out: bf16 [C][R], scaled
__global__ void tconv(const float* __restrict__ in, unsigned short* __restrict__ out,
                      int R, int C, float scale) {
  __shared__ float tile[32][33];
  int bx = blockIdx.x, by = blockIdx.y;
  int tx = threadIdx.x, ty = threadIdx.y;
#pragma unroll
  for (int i = 0; i < 4; ++i)
    tile[ty + i * 8][tx] = in[(long)(by * 32 + ty + i * 8) * C + bx * 32 + tx];
  __syncthreads();
#pragma unroll
  for (int i = 0; i < 4; ++i)
    out[(long)(bx * 32 + ty + i * 8) * R + by * 32 + tx] = f2bf(tile[tx][ty + i * 8] * scale);
}

// C[128][128] = A[128][64] @ B[64][128]   (fp32, tiny)
__global__ void fold_wc(const float* __restrict__ A, const float* __restrict__ Bm,
                        float* __restrict__ Cm) {
  int j = threadIdx.x;  // 128
  int m = blockIdx.x;   // 128
  float acc = 0.f;
#pragma unroll
  for (int l = 0; l < 64; ++l) acc += A[m * 64 + l] * Bm[l * 128 + j];
  Cm[m * 128 + j] = acc;
}

// We[k][h*128+j] = sum_m W[k][h*128+m] * Wc[m][j]
__global__ void make_eff(const float* __restrict__ W, const float* __restrict__ Wc,
                         float* __restrict__ We) {
  int j = threadIdx.x;  // 128
  int k = blockIdx.x;   // 2048
  int h = blockIdx.y;   // 4
  const float* wrow = W + (long)k * 512 + h * 128;
  float acc = 0.f;
#pragma unroll 8
  for (int m = 0; m < 128; ++m) acc += wrow[m] * Wc[m * 128 + j];
  We[(long)k * 512 + h * 128 + j] = acc;
}

// ---------------- GEMM: C[M][N] = A[M][K] @ BT[N][K]^T  (bf16 in, m97 structure) ----------------
// EPI 0: bf16 C row-major; 1: bf16 C transposed ([N][M]); 2: f32 C row-major
template <int EPI>
__global__ __launch_bounds__(256, 2) void gemm_bt(const unsigned short* __restrict__ A,
                                                  const unsigned short* __restrict__ BT,
                                                  void* __restrict__ Cout, int M, int N, int K) {
  __shared__ unsigned short As[128 * 32];
  __shared__ unsigned short Bs[128 * 32];
  const int tid = threadIdx.x;
  const int lane = tid & 63, w = tid >> 6;
  const int wr = w >> 1, wc = w & 1;
  const int c = lane & 15, hi = lane >> 4;
  const int nbn = N >> 7;
  // XCD-aware bijective swizzle (grid % 8 == 0 for all our launches)
  int bid = blockIdx.x;
  bid = (bid & 7) * (gridDim.x >> 3) + (bid >> 3);
  const int bm = bid / nbn, bn = bid % nbn;
  const int row0 = bm << 7, col0 = bn << 7;

  const unsigned short* ga = A + (long)(row0 + (tid >> 2)) * K + ((tid & 3) << 3);
  const unsigned short* gb = BT + (long)(col0 + (tid >> 2)) * K + ((tid & 3) << 3);
  unsigned short* la = As + tid * 8;
  unsigned short* lb = Bs + tid * 8;
  const long sA = (long)64 * K;

  f32x4 acc[4][4] = {};

  for (int k0 = 0; k0 < K; k0 += 32) {
    __syncthreads();
    gll16(ga + k0, la);
    gll16(ga + sA + k0, la + 2048);
    gll16(gb + k0, lb);
    gll16(gb + sA + k0, lb + 2048);
    __syncthreads();
    short8 a[4], b[4];
#pragma unroll
    for (int m = 0; m < 4; ++m)
      a[m] = *(const short8*)&As[(wr * 64 + m * 16 + c) * 32 + hi * 8];
#pragma unroll
    for (int n = 0; n < 4; ++n)
      b[n] = *(const short8*)&Bs[(wc * 64 + n * 16 + c) * 32 + hi * 8];
#pragma unroll
    for (int m = 0; m < 4; ++m)
#pragma unroll
      for (int n = 0; n < 4; ++n) acc[m][n] = MFMA(a[m], b[n], acc[m][n]);
  }

  if (EPI == 0) {
    unsigned short* C = (unsigned short*)Cout;
#pragma unroll
    for (int m = 0; m < 4; ++m) {
      int r0 = row0 + wr * 64 + m * 16 + hi * 4;
#pragma unroll
      for (int n = 0; n < 4; ++n) {
        int cc = col0 + wc * 64 + n * 16 + c;
#pragma unroll
        for (int j = 0; j < 4; ++j) C[(long)(r0 + j) * N + cc] = f2bf(acc[m][n][j]);
      }
    }
  } else if (EPI == 1) {
    unsigned short* C = (unsigned short*)Cout;  // [N][M]
#pragma unroll
    for (int m = 0; m < 4; ++m) {
      int r0 = row0 + wr * 64 + m * 16 + hi * 4;
#pragma unroll
      for (int n = 0; n < 4; ++n) {
        int cc = col0 + wc * 64 + n * 16 + c;
        us4 v;
#pragma unroll
        for (int j = 0; j < 4; ++j) v[j] = f2bf(acc[m][n][j]);
        *(us4*)&C[(long)cc * M + r0] = v;
      }
    }
  } else {
    float* C = (float*)Cout;
#pragma unroll
    for (int m = 0; m < 4; ++m) {
      int r0 = row0 + wr * 64 + m * 16 + hi * 4;
#pragma unroll
      for (int n = 0; n < 4; ++n) {
        int cc = col0 + wc * 64 + n * 16 + c;
#pragma unroll
        for (int j = 0; j < 4; ++j) C[(long)(r0 + j) * N + cc] = acc[m][n][j];
      }
    }
  }
}

// ---------------- attention ----------------
// Q: [8192][2048] bf16 (pre-scaled by log2e/sqrt(128) -> base-2 softmax);
// Kr: [8192][512]; VT: [512][8192]; out CTX: [8192][2048] bf16.
// grid (T/64=32, H=16, B=4), 256 threads (4 waves x 16 q-rows).
// T14 reg-staged double-buffer: single K/V LDS buffer (3 blocks/CU), tile t+1
// prefetched into registers under tile t's compute, ds_write after read-barrier.
__global__ __launch_bounds__(256, 3) void attn_kernel(const unsigned short* __restrict__ Q,
                                                      const unsigned short* __restrict__ Kr,
                                                      const unsigned short* __restrict__ VT,
                                                      unsigned short* __restrict__ CTX) {
  const int qt = blockIdx.x, h = blockIdx.y, b = blockIdx.z;
  const int kvh = h >> 2;
  const int tid = threadIdx.x, lane = tid & 63, w = tid >> 6;
  const int c = lane & 15, hi = lane >> 4;

  __shared__ unsigned short Ks[64 * 128];   // [key][d], XOR-swizzled
  __shared__ unsigned short Vs[128 * 64];   // [d][key], XOR-swizzled
  __shared__ unsigned short Ps[4][16 * 68]; // per-wave P, stride 68

  const long qrow = (long)(b * 2048 + qt * 64 + w * 16 + c);
  short8 aq[4];
#pragma unroll
  for (int kk = 0; kk < 4; ++kk)
    aq[kk] = *(const short8*)&Q[qrow * 2048 + h * 128 + kk * 32 + hi * 8];

  f32x4 acc[8] = {};
  float mrow[4] = {-1e30f, -1e30f, -1e30f, -1e30f};
  float lrow[4] = {0.f, 0.f, 0.f, 0.f};

  const unsigned short* kbase = Kr + (long)b * 2048 * 512 + kvh * 128;
  const unsigned short* vbase = VT + (long)kvh * 128 * 8192 + b * 2048;

  // per-thread staging geometry: LINEAR global source, XOR-swizzled LDS dest
  long kgo[4], vgo[4];
  int kds[4], vds[4];
#pragma unroll
  for (int i = 0; i < 4; ++i) {
    int p = i * 4096 + tid * 16;  // byte offset within 16 KB tile
    int key = p >> 8;             // K: row (key), 256 B/row
    kgo[i] = (long)key * 512 + ((p & 255) >> 1);
    kds[i] = p ^ ((key & 7) << 4);
    int d = p >> 7;               // V^T: row (d), 128 B/row
    vgo[i] = (long)d * 8192 + ((p & 127) >> 1);
    vds[i] = p ^ ((d & 7) << 4);
  }

  short8 kreg[4], vreg[4];
  // prologue: stage tile 0 through registers
#pragma unroll
  for (int i = 0; i < 4; ++i) kreg[i] = *(const short8*)(kbase + kgo[i]);
#pragma unroll
  for (int i = 0; i < 4; ++i) vreg[i] = *(const short8*)(vbase + vgo[i]);
#pragma unroll
  for (int i = 0; i < 4; ++i) *(short8*)((char*)Ks + kds[i]) = kreg[i];
#pragma unroll
  for (int i = 0; i < 4; ++i) *(short8*)((char*)Vs + vds[i]) = vreg[i];
  __syncthreads();

  for (int t = 0; t < 32; ++t) {
    // issue tile t+1 global loads; latency hides under tile t compute
    if (t < 31) {
      const long ko = (long)(t + 1) * 64 * 512;
      const int vo = (t + 1) * 64;
#pragma unroll
      for (int i = 0; i < 4; ++i) kreg[i] = *(const short8*)(kbase + ko + kgo[i]);
#pragma unroll
      for (int i = 0; i < 4; ++i) vreg[i] = *(const short8*)(vbase + vo + vgo[i]);
    }

    // S = Q K^T  (16 q-rows x 64 keys per wave)
    f32x4 s[4] = {};
#pragma unroll
    for (int n = 0; n < 4; ++n) {
      int r = n * 16 + c;
#pragma unroll
      for (int kk = 0; kk < 4; ++kk) {
        int lb = r * 256 + kk * 64 + hi * 16;
        int sb = lb ^ ((r & 7) << 4);
        short8 bk = *(const short8*)((const char*)Ks + sb);
        s[n] = MFMA(aq[kk], bk, s[n]);
      }
    }

    // online softmax in base-2, defer-max (THR = 11 in log2 units)
    float pv[4][4];
#pragma unroll
    for (int j = 0; j < 4; ++j) {
      float tmax = fmaxf(fmaxf(s[0][j], s[1][j]), fmaxf(s[2][j], s[3][j]));
      tmax = fmaxf(tmax, __shfl_xor(tmax, 1));
      tmax = fmaxf(tmax, __shfl_xor(tmax, 2));
      tmax = fmaxf(tmax, __shfl_xor(tmax, 4));
      tmax = fmaxf(tmax, __shfl_xor(tmax, 8));
      if (tmax > mrow[j] + 11.0f) {
        float sc = __builtin_amdgcn_exp2f(mrow[j] - tmax);
        mrow[j] = tmax;
        lrow[j] *= sc;
#pragma unroll
        for (int n8 = 0; n8 < 8; ++n8) acc[n8][j] *= sc;
      }
      float ps = 0.f;
#pragma unroll
      for (int n = 0; n < 4; ++n) {
        float e = __builtin_amdgcn_exp2f(s[n][j] - mrow[j]);
        pv[n][j] = e;
        ps += e;
      }
      ps += __shfl_xor(ps, 1);
      ps += __shfl_xor(ps, 2);
      ps += __shfl_xor(ps, 4);
      ps += __shfl_xor(ps, 8);
      lrow[j] += ps;
    }

    // P -> per-wave LDS (no barrier needed: same-wave write->read)
#pragma unroll
    for (int n = 0; n < 4; ++n)
#pragma unroll
      for (int j = 0; j < 4; ++j)
        Ps[w][(hi * 4 + j) * 68 + n * 16 + c] = f2bf(pv[n][j]);

    short8 ap[2];
    {
      const char* pb = (const char*)(Ps[w]) + c * 136 + hi * 16;
#pragma unroll
      for (int kk = 0; kk < 2; ++kk) {
        short4v lo4 = *(const short4v*)(pb + kk * 64);
        short4v hi4 = *(const short4v*)(pb + kk * 64 + 8);
        short8 tt;
        tt[0] = lo4[0]; tt[1] = lo4[1]; tt[2] = lo4[2]; tt[3] = lo4[3];
        tt[4] = hi4[0]; tt[5] = hi4[1]; tt[6] = hi4[2]; tt[7] = hi4[3];
        ap[kk] = tt;
      }
    }

    // ctx += P V
#pragma unroll
    for (int n = 0; n < 8; ++n) {
      int r = n * 16 + c;
#pragma unroll
      for (int kk = 0; kk < 2; ++kk) {
        int lb = r * 128 + kk * 64 + hi * 16;
        int sb = lb ^ ((r & 7) << 4);
        short8 bv = *(const short8*)((const char*)Vs + sb);
        acc[n] = MFMA(ap[kk], bv, acc[n]);
      }
    }

    __syncthreads();  // all waves done READING Ks/Vs for tile t
    if (t < 31) {
#pragma unroll
      for (int i = 0; i < 4; ++i) *(short8*)((char*)Ks + kds[i]) = kreg[i];
#pragma unroll
      for (int i = 0; i < 4; ++i) *(short8*)((char*)Vs + vds[i]) = vreg[i];
    }
    __syncthreads();  // tile t+1 visible
  }

#pragma unroll
  for (int j = 0; j < 4; ++j) {
    float inv = 1.0f / lrow[j];
    long r = (long)(b * 2048 + qt * 64 + w * 16 + hi * 4 + j);
#pragma unroll
    for (int n = 0; n < 8; ++n)
      CTX[r * 2048 + h * 128 + n * 16 + c] = f2bf(acc[n][j] * inv);
  }
}

// ---------------- launch ----------------

extern "C" void kernel_launch(void* const* d_in, const int* in_sizes, int n_in, void* d_out,
                              int out_size, void* d_ws, size_t ws_size, hipStream_t stream) {
  (void)in_sizes; (void)n_in; (void)out_size; (void)ws_size;
  const float* x    = (const float*)d_in[0];
  const float* W_q  = (const float*)d_in[1];
  const float* W_k  = (const float*)d_in[2];
  const float* W_v  = (const float*)d_in[3];
  const float* Wk2l = (const float*)d_in[4];
  const float* Wv2l = (const float*)d_in[5];
  const float* Wkfl = (const float*)d_in[6];
  const float* Wvfl = (const float*)d_in[7];
  const float* W_o  = (const float*)d_in[8];
  float* out = (float*)d_out;

  char* ws = (char*)d_ws;
  unsigned short* Xb   = (unsigned short*)(ws + 0);          // 32 MiB (reused as CTXb)
  unsigned short* Qb   = (unsigned short*)(ws + 33554432);   // 32 MiB
  unsigned short* KRb  = (unsigned short*)(ws + 67108864);   // 8 MiB
  unsigned short* VTb  = (unsigned short*)(ws + 75497472);   // 8 MiB
  unsigned short* WqT  = (unsigned short*)(ws + 83886080);   // 8 MiB
  unsigned short* WoT  = (unsigned short*)(ws + 92274688);   // 8 MiB
  unsigned short* WkeT = (unsigned short*)(ws + 100663296);  // 2 MiB
  unsigned short* WveT = (unsigned short*)(ws + 102760448);  // 2 MiB
  float* Wkc    = (float*)(ws + 104857600);                  // 64 KiB
  float* Wvc    = (float*)(ws + 104923136);                  // 64 KiB
  float* Wstage = (float*)(ws + 104988672);                  // 4 MiB
  unsigned short* CTXb = Xb;

  // dtype conversion + weight folding (W_q scale includes 1/sqrt(Dh) AND log2e)
  conv_bf16<<<2048, 256, 0, stream>>>(x, Xb, 16777216 / 4);
  tconv<<<dim3(64, 64), dim3(32, 8), 0, stream>>>(W_q, WqT, 2048, 2048,
                                                  (float)(0.088388347648318447 * 1.4426950408889634));
  tconv<<<dim3(64, 64), dim3(32, 8), 0, stream>>>(W_o, WoT, 2048, 2048, 1.0f);
  fold_wc<<<128, 128, 0, stream>>>(Wk2l, Wkfl, Wkc);
  fold_wc<<<128, 128, 0, stream>>>(Wv2l, Wvfl, Wvc);
  make_eff<<<dim3(2048, 4), 128, 0, stream>>>(W_k, Wkc, Wstage);
  tconv<<<dim3(16, 64), dim3(32, 8), 0, stream>>>(Wstage, WkeT, 2048, 512, 1.0f);
  make_eff<<<dim3(2048, 4), 128, 0, stream>>>(W_v, Wvc, Wstage);
  tconv<<<dim3(16, 64), dim3(32, 8), 0, stream>>>(Wstage, WveT, 2048, 512, 1.0f);

  // projections
  gemm_bt<0><<<1024, 256, 0, stream>>>(Xb, WqT, Qb, 8192, 2048, 2048);
  gemm_bt<0><<<256, 256, 0, stream>>>(Xb, WkeT, KRb, 8192, 512, 2048);
  gemm_bt<1><<<256, 256, 0, stream>>>(Xb, WveT, VTb, 8192, 512, 2048);  // V stored transposed

  // attention
  attn_kernel<<<dim3(32, 16, 4), 256, 0, stream>>>(Qb, KRb, VTb, CTXb);

  // output projection -> fp32 d_out
  gemm_bt<2><<<1024, 256, 0, stream>>>(CTXb, WoT, out, 8192, 2048, 2048);
}

// Round 6
// 488.205 us; speedup vs baseline: 1.3656x; 1.3474x over previous
//
#include <hip/hip_runtime.h>

typedef __attribute__((ext_vector_type(8))) short short8;
typedef __attribute__((ext_vector_type(4))) float f32x4;
typedef __attribute__((ext_vector_type(16))) float f32x16;
typedef __attribute__((ext_vector_type(4))) unsigned short us4;
typedef __attribute__((ext_vector_type(4))) int i32x4;

__device__ __forceinline__ unsigned short f2bf(float f) {
  unsigned u = __builtin_bit_cast(unsigned, f);
  u += 0x7FFFu + ((u >> 16) & 1u);
  return (unsigned short)(u >> 16);
}

// RNE bf16 pair pack
__device__ __forceinline__ int packbf(float lo, float hi) {
  return (int)((unsigned)f2bf(lo) | ((unsigned)f2bf(hi) << 16));
}

__device__ __forceinline__ void gll16(const void* g, void* l) {
  __builtin_amdgcn_global_load_lds(
      (const __attribute__((address_space(1))) void*)g,
      (__attribute__((address_space(3))) void*)l, 16, 0, 0);
}

__device__ __forceinline__ f32x4 MFMA(short8 a, short8 b, f32x4 c) {
  return __builtin_amdgcn_mfma_f32_16x16x32_bf16(a, b, c, 0, 0, 0);
}
__device__ __forceinline__ f32x16 MFMA32(short8 a, short8 b, f32x16 c) {
  return __builtin_amdgcn_mfma_f32_32x32x16_bf16(a, b, c, 0, 0, 0);
}

// ---------------- prep kernels ----------------

__global__ void conv_bf16(const float* __restrict__ in, unsigned short* __restrict__ out, int n4) {
  for (int i = blockIdx.x * blockDim.x + threadIdx.x; i < n4; i += gridDim.x * blockDim.x) {
    float4 v = ((const float4*)in)[i];
    us4 o;
    o[0] = f2bf(v.x); o[1] = f2bf(v.y); o[2] = f2bf(v.z); o[3] = f2bf(v.w);
    ((us4*)out)[i] = o;
  }
}

// in: fp32 [R][C] -> out: bf16 [C][R], scaled
__global__ void tconv(const float* __restrict__ in, unsigned short* __restrict__ out,
                      int R, int C, float scale) {
  __shared__ float tile[32][33];
  int bx = blockIdx.x, by = blockIdx.y;
  int tx = threadIdx.x, ty = threadIdx.y;
#pragma unroll
  for (int i = 0; i < 4; ++i)
    tile[ty + i * 8][tx] = in[(long)(by * 32 + ty + i * 8) * C + bx * 32 + tx];
  __syncthreads();
#pragma unroll
  for (int i = 0; i < 4; ++i)
    out[(long)(bx * 32 + ty + i * 8) * R + by * 32 + tx] = f2bf(tile[tx][ty + i * 8] * scale);
}

// C[128][128] = A[128][64] @ B[64][128]   (fp32, tiny)
__global__ void fold_wc(const float* __restrict__ A, const float* __restrict__ Bm,
                        float* __restrict__ Cm) {
  int j = threadIdx.x;
  int m = blockIdx.x;
  float acc = 0.f;
#pragma unroll
  for (int l = 0; l < 64; ++l) acc += A[m * 64 + l] * Bm[l * 128 + j];
  Cm[m * 128 + j] = acc;
}

// We[k][h*128+j] = sum_m W[k][h*128+m] * Wc[m][j]
__global__ void make_eff(const float* __restrict__ W, const float* __restrict__ Wc,
                         float* __restrict__ We) {
  int j = threadIdx.x;
  int k = blockIdx.x;
  int h = blockIdx.y;
  const float* wrow = W + (long)k * 512 + h * 128;
  float acc = 0.f;
#pragma unroll 8
  for (int m = 0; m < 128; ++m) acc += wrow[m] * Wc[m * 128 + j];
  We[(long)k * 512 + h * 128 + j] = acc;
}

// ---------------- GEMM: C[M][N] = A[M][K] @ BT[N][K]^T  (bf16 in, m97 structure) ----------------
template <int EPI>
__global__ __launch_bounds__(256, 2) void gemm_bt(const unsigned short* __restrict__ A,
                                                  const unsigned short* __restrict__ BT,
                                                  void* __restrict__ Cout, int M, int N, int K) {
  __shared__ unsigned short As[128 * 32];
  __shared__ unsigned short Bs[128 * 32];
  const int tid = threadIdx.x;
  const int lane = tid & 63, w = tid >> 6;
  const int wr = w >> 1, wc = w & 1;
  const int c = lane & 15, hi = lane >> 4;
  const int nbn = N >> 7;
  int bid = blockIdx.x;
  bid = (bid & 7) * (gridDim.x >> 3) + (bid >> 3);
  const int bm = bid / nbn, bn = bid % nbn;
  const int row0 = bm << 7, col0 = bn << 7;

  const unsigned short* ga = A + (long)(row0 + (tid >> 2)) * K + ((tid & 3) << 3);
  const unsigned short* gb = BT + (long)(col0 + (tid >> 2)) * K + ((tid & 3) << 3);
  unsigned short* la = As + tid * 8;
  unsigned short* lb = Bs + tid * 8;
  const long sA = (long)64 * K;

  f32x4 acc[4][4] = {};

  for (int k0 = 0; k0 < K; k0 += 32) {
    __syncthreads();
    gll16(ga + k0, la);
    gll16(ga + sA + k0, la + 2048);
    gll16(gb + k0, lb);
    gll16(gb + sA + k0, lb + 2048);
    __syncthreads();
    short8 a[4], b[4];
#pragma unroll
    for (int m = 0; m < 4; ++m)
      a[m] = *(const short8*)&As[(wr * 64 + m * 16 + c) * 32 + hi * 8];
#pragma unroll
    for (int n = 0; n < 4; ++n)
      b[n] = *(const short8*)&Bs[(wc * 64 + n * 16 + c) * 32 + hi * 8];
#pragma unroll
    for (int m = 0; m < 4; ++m)
#pragma unroll
      for (int n = 0; n < 4; ++n) acc[m][n] = MFMA(a[m], b[n], acc[m][n]);
  }

  if (EPI == 0) {
    unsigned short* C = (unsigned short*)Cout;
#pragma unroll
    for (int m = 0; m < 4; ++m) {
      int r0 = row0 + wr * 64 + m * 16 + hi * 4;
#pragma unroll
      for (int n = 0; n < 4; ++n) {
        int cc = col0 + wc * 64 + n * 16 + c;
#pragma unroll
        for (int j = 0; j < 4; ++j) C[(long)(r0 + j) * N + cc] = f2bf(acc[m][n][j]);
      }
    }
  } else if (EPI == 1) {
    unsigned short* C = (unsigned short*)Cout;  // [N][M]
#pragma unroll
    for (int m = 0; m < 4; ++m) {
      int r0 = row0 + wr * 64 + m * 16 + hi * 4;
#pragma unroll
      for (int n = 0; n < 4; ++n) {
        int cc = col0 + wc * 64 + n * 16 + c;
        us4 v;
#pragma unroll
        for (int j = 0; j < 4; ++j) v[j] = f2bf(acc[m][n][j]);
        *(us4*)&C[(long)cc * M + r0] = v;
      }
    }
  } else {
    float* C = (float*)Cout;
#pragma unroll
    for (int m = 0; m < 4; ++m) {
      int r0 = row0 + wr * 64 + m * 16 + hi * 4;
#pragma unroll
      for (int n = 0; n < 4; ++n) {
        int cc = col0 + wc * 64 + n * 16 + c;
#pragma unroll
        for (int j = 0; j < 4; ++j) C[(long)(r0 + j) * N + cc] = acc[m][n][j];
      }
    }
  }
}

// ---------------- attention: 8-warp 32x32 swapped-QK^T structure ----------------
// Q: [8192][2048] bf16 (pre-scaled by log2e/sqrt(128)); Kr: [8192][512]; VT: [512][8192];
// CTX: [8192][2048] bf16. grid (T/256=8, H=16, B=4), 512 threads = 8 waves x 32 q-rows.
// All cross-half exchanges via __shfl_xor(.,32) — no asm register-aliasing hazards.
__global__ __launch_bounds__(512, 1) void attn_kernel(const unsigned short* __restrict__ Q,
                                                      const unsigned short* __restrict__ Kr,
                                                      const unsigned short* __restrict__ VT,
                                                      unsigned short* __restrict__ CTX) {
  const int qt = blockIdx.x, h = blockIdx.y, b = blockIdx.z;
  const int kvh = h >> 2;
  const int tid = threadIdx.x, lane = tid & 63, w = tid >> 6;
  const int q31 = lane & 31, hi = lane >> 5, l7 = lane & 7;

  __shared__ unsigned short Ks[2][64 * 128];  // [key][d] XOR-swizzled
  __shared__ unsigned short Vs[2][128 * 64];  // [d][key] XOR-swizzled
  __shared__ float tab[8][32];                // per-warp q-indexed broadcast table

  // Q fragments: B-operand of mfma(K,Q): lane holds Q[q31][st*16 + hi*8 + j]
  const long qrow = (long)(b * 2048 + qt * 256 + w * 32 + q31);
  short8 qf[8];
#pragma unroll
  for (int st = 0; st < 8; ++st)
    qf[st] = *(const short8*)&Q[qrow * 2048 + h * 128 + st * 16 + hi * 8];

  f32x16 acc[4] = {};
  float mrow = -1e30f, lrow = 0.f;

  const unsigned short* kbase = Kr + (long)b * 2048 * 512 + kvh * 128;
  const unsigned short* vbase = VT + (long)kvh * 128 * 8192 + b * 2048;

  // staging: linear LDS dest, pre-swizzled global source (2 x 16B per thread per tile each)
  int kp[2], vp[2];
  long kgo[2], vgo[2];
#pragma unroll
  for (int i = 0; i < 2; ++i) {
    int p = i * 8192 + tid * 16;
    int key = p >> 8;
    kgo[i] = (long)key * 512 + (((p & 255) ^ ((key & 7) << 4)) >> 1);
    kp[i] = p;
    int d = p >> 7;
    vgo[i] = (long)d * 8192 + (((p & 127) ^ ((d & 7) << 4)) >> 1);
    vp[i] = p;
  }

#define STAGE(T, BUF)                                        \
  do {                                                       \
    const long ko_ = (long)(T) * 32768;                      \
    const int vo_ = (T) * 64;                                \
    gll16(kbase + ko_ + kgo[0], (char*)Ks[BUF] + kp[0]);     \
    gll16(kbase + ko_ + kgo[1], (char*)Ks[BUF] + kp[1]);     \
    gll16(vbase + vo_ + vgo[0], (char*)Vs[BUF] + vp[0]);     \
    gll16(vbase + vo_ + vgo[1], (char*)Vs[BUF] + vp[1]);     \
  } while (0)

  STAGE(0, 0);
  __syncthreads();

  for (int t = 0; t < 32; ++t) {
    const int cur = t & 1;
    if (t < 31) STAGE(t + 1, cur ^ 1);

    const char* ks = (const char*)Ks[cur];
    const char* vs = (const char*)Vs[cur];

    // S = mfma(K, Q): s0 = keys 0-31, s1 = keys 32-63; lane col = own q
    f32x16 s0 = {}, s1 = {};
    __builtin_amdgcn_s_setprio(1);
#pragma unroll
    for (int st = 0; st < 8; ++st) {
      int col = st * 32 + hi * 16;
      short8 k0 = *(const short8*)(ks + ((q31 * 256 + col) ^ (l7 << 4)));
      short8 k1 = *(const short8*)(ks + (((32 + q31) * 256 + col) ^ (l7 << 4)));
      s0 = MFMA32(k0, qf[st], s0);
      s1 = MFMA32(k1, qf[st], s1);
    }
    __builtin_amdgcn_s_setprio(0);

    // row max: 31 in-register fmax + cross-half exchange
    float tl = s0[0];
#pragma unroll
    for (int e = 1; e < 16; ++e) tl = fmaxf(tl, s0[e]);
#pragma unroll
    for (int e = 0; e < 16; ++e) tl = fmaxf(tl, s1[e]);
    tl = fmaxf(tl, __shfl_xor(tl, 32));

    // defer-max rescale (wave-uniform branch; per-q scale broadcast via LDS table)
    if (__any(tl > mrow + 11.0f)) {
      float mn = fmaxf(mrow, tl);
      float sc = __builtin_amdgcn_exp2f(mrow - mn);
      mrow = mn;
      lrow *= sc;
      if (lane < 32) tab[w][lane] = sc;
#pragma unroll
      for (int rg = 0; rg < 16; ++rg) {
        float scr = tab[w][(rg & 3) + 8 * (rg >> 2) + 4 * hi];
#pragma unroll
        for (int dblk = 0; dblk < 4; ++dblk) acc[dblk][rg] *= scr;
      }
    }

    // P = exp2(S - m) in place; row sum
    float sum = 0.f;
#pragma unroll
    for (int e = 0; e < 16; ++e) {
      s0[e] = __builtin_amdgcn_exp2f(s0[e] - mrow);
      sum += s0[e];
    }
#pragma unroll
    for (int e = 0; e < 16; ++e) {
      s1[e] = __builtin_amdgcn_exp2f(s1[e] - mrow);
      sum += s1[e];
    }
    sum += __shfl_xor(sum, 32);
    lrow += sum;

    // pack P -> PV A-frags: RNE packs + shfl_xor(32) cross-half exchange
    short8 ap[4];
#pragma unroll
    for (int kq = 0; kq < 4; ++kq) {
      int a0, a1, a2, a3;
      if (kq == 0) {
        a0 = packbf(s0[0], s0[1]);   a1 = packbf(s0[2], s0[3]);
        a2 = packbf(s0[4], s0[5]);   a3 = packbf(s0[6], s0[7]);
      } else if (kq == 1) {
        a0 = packbf(s0[8], s0[9]);   a1 = packbf(s0[10], s0[11]);
        a2 = packbf(s0[12], s0[13]); a3 = packbf(s0[14], s0[15]);
      } else if (kq == 2) {
        a0 = packbf(s1[0], s1[1]);   a1 = packbf(s1[2], s1[3]);
        a2 = packbf(s1[4], s1[5]);   a3 = packbf(s1[6], s1[7]);
      } else {
        a0 = packbf(s1[8], s1[9]);   a1 = packbf(s1[10], s1[11]);
        a2 = packbf(s1[12], s1[13]); a3 = packbf(s1[14], s1[15]);
      }
      int b0 = __shfl_xor(a0, 32);
      int b1 = __shfl_xor(a1, 32);
      int b2 = __shfl_xor(a2, 32);
      int b3 = __shfl_xor(a3, 32);
      // u0' = hi ? partner_u2 : u0 ; u1' = hi ? partner_u3 : u1
      // u2' = hi ? u2 : partner_u0 ; u3' = hi ? u3 : partner_u1
      i32x4 tt;
      tt[0] = hi ? b2 : a0;
      tt[1] = hi ? b3 : a1;
      tt[2] = hi ? a2 : b0;
      tt[3] = hi ? a3 : b1;
      ap[kq] = __builtin_bit_cast(short8, tt);
    }

    // ctx += P V   (C rows = q, cols = d-in-block; B = V[key][d])
    __builtin_amdgcn_s_setprio(1);
#pragma unroll
    for (int dblk = 0; dblk < 4; ++dblk) {
      int lbb = (dblk * 32 + q31) * 128 + hi * 16;
#pragma unroll
      for (int kq = 0; kq < 4; ++kq) {
        short8 vv = *(const short8*)(vs + ((lbb + kq * 32) ^ (l7 << 4)));
        acc[dblk] = MFMA32(ap[kq], vv, acc[dblk]);
      }
    }
    __builtin_amdgcn_s_setprio(0);

    __syncthreads();
  }

  // epilogue: per-q 1/l via broadcast table; C-layout rows
  if (lane < 32) tab[w][lane] = 1.0f / lrow;
#pragma unroll
  for (int rg = 0; rg < 16; ++rg) {
    int qr = (rg & 3) + 8 * (rg >> 2) + 4 * hi;
    float il = tab[w][qr];
    long grow = (long)(b * 2048 + qt * 256 + w * 32 + qr);
#pragma unroll
    for (int dblk = 0; dblk < 4; ++dblk)
      CTX[grow * 2048 + h * 128 + dblk * 32 + q31] = f2bf(acc[dblk][rg] * il);
  }
#undef STAGE
}

// ---------------- launch ----------------

extern "C" void kernel_launch(void* const* d_in, const int* in_sizes, int n_in, void* d_out,
                              int out_size, void* d_ws, size_t ws_size, hipStream_t stream) {
  (void)in_sizes; (void)n_in; (void)out_size; (void)ws_size;
  const float* x    = (const float*)d_in[0];
  const float* W_q  = (const float*)d_in[1];
  const float* W_k  = (const float*)d_in[2];
  const float* W_v  = (const float*)d_in[3];
  const float* Wk2l = (const float*)d_in[4];
  const float* Wv2l = (const float*)d_in[5];
  const float* Wkfl = (const float*)d_in[6];
  const float* Wvfl = (const float*)d_in[7];
  const float* W_o  = (const float*)d_in[8];
  float* out = (float*)d_out;

  char* ws = (char*)d_ws;
  unsigned short* Xb   = (unsigned short*)(ws + 0);          // 32 MiB (reused as CTXb)
  unsigned short* Qb   = (unsigned short*)(ws + 33554432);   // 32 MiB
  unsigned short* KRb  = (unsigned short*)(ws + 67108864);   // 8 MiB
  unsigned short* VTb  = (unsigned short*)(ws + 75497472);   // 8 MiB
  unsigned short* WqT  = (unsigned short*)(ws + 83886080);   // 8 MiB
  unsigned short* WoT  = (unsigned short*)(ws + 92274688);   // 8 MiB
  unsigned short* WkeT = (unsigned short*)(ws + 100663296);  // 2 MiB
  unsigned short* WveT = (unsigned short*)(ws + 102760448);  // 2 MiB
  float* Wkc    = (float*)(ws + 104857600);                  // 64 KiB
  float* Wvc    = (float*)(ws + 104923136);                  // 64 KiB
  float* Wstage = (float*)(ws + 104988672);                  // 4 MiB
  unsigned short* CTXb = Xb;

  // dtype conversion + weight folding (W_q scale includes 1/sqrt(Dh) AND log2e)
  conv_bf16<<<2048, 256, 0, stream>>>(x, Xb, 16777216 / 4);
  tconv<<<dim3(64, 64), dim3(32, 8), 0, stream>>>(W_q, WqT, 2048, 2048,
                                                  (float)(0.088388347648318447 * 1.4426950408889634));
  tconv<<<dim3(64, 64), dim3(32, 8), 0, stream>>>(W_o, WoT, 2048, 2048, 1.0f);
  fold_wc<<<128, 128, 0, stream>>>(Wk2l, Wkfl, Wkc);
  fold_wc<<<128, 128, 0, stream>>>(Wv2l, Wvfl, Wvc);
  make_eff<<<dim3(2048, 4), 128, 0, stream>>>(W_k, Wkc, Wstage);
  tconv<<<dim3(16, 64), dim3(32, 8), 0, stream>>>(Wstage, WkeT, 2048, 512, 1.0f);
  make_eff<<<dim3(2048, 4), 128, 0, stream>>>(W_v, Wvc, Wstage);
  tconv<<<dim3(16, 64), dim3(32, 8), 0, stream>>>(Wstage, WveT, 2048, 512, 1.0f);

  // projections
  gemm_bt<0><<<1024, 256, 0, stream>>>(Xb, WqT, Qb, 8192, 2048, 2048);
  gemm_bt<0><<<256, 256, 0, stream>>>(Xb, WkeT, KRb, 8192, 512, 2048);
  gemm_bt<1><<<256, 256, 0, stream>>>(Xb, WveT, VTb, 8192, 512, 2048);  // V stored transposed

  // attention (8-warp 32x32 structure)
  attn_kernel<<<dim3(8, 16, 4), 512, 0, stream>>>(Qb, KRb, VTb, CTXb);

  // output projection -> fp32 d_out
  gemm_bt<2><<<1024, 256, 0, stream>>>(CTXb, WoT, out, 8192, 2048, 2048);
}

// Round 7
// 487.036 us; speedup vs baseline: 1.3689x; 1.0024x over previous
//
#include <hip/hip_runtime.h>

typedef __attribute__((ext_vector_type(8))) short short8;
typedef __attribute__((ext_vector_type(4))) float f32x4;
typedef __attribute__((ext_vector_type(16))) float f32x16;
typedef __attribute__((ext_vector_type(4))) unsigned short us4;
typedef __attribute__((ext_vector_type(4))) int i32x4;

__device__ __forceinline__ unsigned short f2bf(float f) {
  unsigned u = __builtin_bit_cast(unsigned, f);
  u += 0x7FFFu + ((u >> 16) & 1u);
  return (unsigned short)(u >> 16);
}

// RNE bf16 pair pack
__device__ __forceinline__ int packbf(float lo, float hi) {
  return (int)((unsigned)f2bf(lo) | ((unsigned)f2bf(hi) << 16));
}

__device__ __forceinline__ void gll16(const void* g, void* l) {
  __builtin_amdgcn_global_load_lds(
      (const __attribute__((address_space(1))) void*)g,
      (__attribute__((address_space(3))) void*)l, 16, 0, 0);
}

__device__ __forceinline__ f32x4 MFMA(short8 a, short8 b, f32x4 c) {
  return __builtin_amdgcn_mfma_f32_16x16x32_bf16(a, b, c, 0, 0, 0);
}
__device__ __forceinline__ f32x16 MFMA32(short8 a, short8 b, f32x16 c) {
  return __builtin_amdgcn_mfma_f32_32x32x16_bf16(a, b, c, 0, 0, 0);
}

// ---------------- prep kernels ----------------

__global__ void conv_bf16(const float* __restrict__ in, unsigned short* __restrict__ out, int n4) {
  for (int i = blockIdx.x * blockDim.x + threadIdx.x; i < n4; i += gridDim.x * blockDim.x) {
    float4 v = ((const float4*)in)[i];
    us4 o;
    o[0] = f2bf(v.x); o[1] = f2bf(v.y); o[2] = f2bf(v.z); o[3] = f2bf(v.w);
    ((us4*)out)[i] = o;
  }
}

// in: fp32 [R][C] -> out: bf16 [C][R], scaled
__global__ void tconv(const float* __restrict__ in, unsigned short* __restrict__ out,
                      int R, int C, float scale) {
  __shared__ float tile[32][33];
  int bx = blockIdx.x, by = blockIdx.y;
  int tx = threadIdx.x, ty = threadIdx.y;
#pragma unroll
  for (int i = 0; i < 4; ++i)
    tile[ty + i * 8][tx] = in[(long)(by * 32 + ty + i * 8) * C + bx * 32 + tx];
  __syncthreads();
#pragma unroll
  for (int i = 0; i < 4; ++i)
    out[(long)(bx * 32 + ty + i * 8) * R + by * 32 + tx] = f2bf(tile[tx][ty + i * 8] * scale);
}

// C[128][128] = A[128][64] @ B[64][128]   (fp32, tiny)
__global__ void fold_wc(const float* __restrict__ A, const float* __restrict__ Bm,
                        float* __restrict__ Cm) {
  int j = threadIdx.x;
  int m = blockIdx.x;
  float acc = 0.f;
#pragma unroll
  for (int l = 0; l < 64; ++l) acc += A[m * 64 + l] * Bm[l * 128 + j];
  Cm[m * 128 + j] = acc;
}

// We[k][h*128+j] = sum_m W[k][h*128+m] * Wc[m][j]
__global__ void make_eff(const float* __restrict__ W, const float* __restrict__ Wc,
                         float* __restrict__ We) {
  int j = threadIdx.x;
  int k = blockIdx.x;
  int h = blockIdx.y;
  const float* wrow = W + (long)k * 512 + h * 128;
  float acc = 0.f;
#pragma unroll 8
  for (int m = 0; m < 128; ++m) acc += wrow[m] * Wc[m * 128 + j];
  We[(long)k * 512 + h * 128 + j] = acc;
}

// ---------------- GEMM 128x128 (m97 structure) — used for K/V projections ----------------
// EPI 0: bf16 C row-major; 1: bf16 C transposed ([N][M]); 2: f32 C row-major
template <int EPI>
__global__ __launch_bounds__(256, 2) void gemm_bt(const unsigned short* __restrict__ A,
                                                  const unsigned short* __restrict__ BT,
                                                  void* __restrict__ Cout, int M, int N, int K) {
  __shared__ unsigned short As[128 * 32];
  __shared__ unsigned short Bs[128 * 32];
  const int tid = threadIdx.x;
  const int lane = tid & 63, w = tid >> 6;
  const int wr = w >> 1, wc = w & 1;
  const int c = lane & 15, hi = lane >> 4;
  const int nbn = N >> 7;
  int bid = blockIdx.x;
  bid = (bid & 7) * (gridDim.x >> 3) + (bid >> 3);
  const int bm = bid / nbn, bn = bid % nbn;
  const int row0 = bm << 7, col0 = bn << 7;

  const unsigned short* ga = A + (long)(row0 + (tid >> 2)) * K + ((tid & 3) << 3);
  const unsigned short* gb = BT + (long)(col0 + (tid >> 2)) * K + ((tid & 3) << 3);
  unsigned short* la = As + tid * 8;
  unsigned short* lb = Bs + tid * 8;
  const long sA = (long)64 * K;

  f32x4 acc[4][4] = {};

  for (int k0 = 0; k0 < K; k0 += 32) {
    __syncthreads();
    gll16(ga + k0, la);
    gll16(ga + sA + k0, la + 2048);
    gll16(gb + k0, lb);
    gll16(gb + sA + k0, lb + 2048);
    __syncthreads();
    short8 a[4], b[4];
#pragma unroll
    for (int m = 0; m < 4; ++m)
      a[m] = *(const short8*)&As[(wr * 64 + m * 16 + c) * 32 + hi * 8];
#pragma unroll
    for (int n = 0; n < 4; ++n)
      b[n] = *(const short8*)&Bs[(wc * 64 + n * 16 + c) * 32 + hi * 8];
#pragma unroll
    for (int m = 0; m < 4; ++m)
#pragma unroll
      for (int n = 0; n < 4; ++n) acc[m][n] = MFMA(a[m], b[n], acc[m][n]);
  }

  if (EPI == 0) {
    unsigned short* C = (unsigned short*)Cout;
#pragma unroll
    for (int m = 0; m < 4; ++m) {
      int r0 = row0 + wr * 64 + m * 16 + hi * 4;
#pragma unroll
      for (int n = 0; n < 4; ++n) {
        int cc = col0 + wc * 64 + n * 16 + c;
#pragma unroll
        for (int j = 0; j < 4; ++j) C[(long)(r0 + j) * N + cc] = f2bf(acc[m][n][j]);
      }
    }
  } else if (EPI == 1) {
    unsigned short* C = (unsigned short*)Cout;  // [N][M]
#pragma unroll
    for (int m = 0; m < 4; ++m) {
      int r0 = row0 + wr * 64 + m * 16 + hi * 4;
#pragma unroll
      for (int n = 0; n < 4; ++n) {
        int cc = col0 + wc * 64 + n * 16 + c;
        us4 v;
#pragma unroll
        for (int j = 0; j < 4; ++j) v[j] = f2bf(acc[m][n][j]);
        *(us4*)&C[(long)cc * M + r0] = v;
      }
    }
  } else {
    float* C = (float*)Cout;
#pragma unroll
    for (int m = 0; m < 4; ++m) {
      int r0 = row0 + wr * 64 + m * 16 + hi * 4;
#pragma unroll
      for (int n = 0; n < 4; ++n) {
        int cc = col0 + wc * 64 + n * 16 + c;
#pragma unroll
        for (int j = 0; j < 4; ++j) C[(long)(r0 + j) * N + cc] = acc[m][n][j];
      }
    }
  }
}

// ---------------- GEMM 256x256, BK=32 ring-4 pipeline, counted vmcnt (T3+T4) ----------------
// 512 threads = 8 waves (2M x 4N); per-wave output 128x64; lookahead-3 staging into a
// 4-slot LDS ring (slot u%4 read while u+1..u+3 in flight) -> no drain-to-0 in main loop.
template <int EPI>
__global__ __launch_bounds__(512, 1) void gemm256(const unsigned short* __restrict__ A,
                                                  const unsigned short* __restrict__ BT,
                                                  void* __restrict__ Cout, int M, int N, int K) {
  __shared__ unsigned short S[4][2][8192];  // [slot][A=0/B=1][256 rows x 32 cols] = 128 KiB
  const int tid = threadIdx.x;
  const int lane = tid & 63, w = tid >> 6;
  const int wr = w >> 2, wc = w & 3;  // 2 x 4 wave grid
  const int c = lane & 15, hi = lane >> 4;
  const int nbn = N >> 8;
  int bid = blockIdx.x;
  bid = (bid & 7) * (gridDim.x >> 3) + (bid >> 3);  // XCD swizzle (grid % 8 == 0)
  const int bm = bid / nbn, bn = bid % nbn;
  const int row0 = bm << 8, col0 = bn << 8;

  // staging sources: thread tid loads 16B of row (tid>>2), col-bytes (tid&3)*16, halves 0/128
  const unsigned short* ga0 = A + (long)(row0 + (tid >> 2)) * K + ((tid & 3) << 3);
  const unsigned short* ga1 = A + (long)(row0 + 128 + (tid >> 2)) * K + ((tid & 3) << 3);
  const unsigned short* gb0 = BT + (long)(col0 + (tid >> 2)) * K + ((tid & 3) << 3);
  const unsigned short* gb1 = BT + (long)(col0 + 128 + (tid >> 2)) * K + ((tid & 3) << 3);
  const int d0 = tid * 16;  // linear LDS dest byte offset within an 8 KiB pass

#define STG(U)                                            \
  do {                                                    \
    const int s_ = (U) & 3;                               \
    const int ko_ = (U) * 32;                             \
    gll16(ga0 + ko_, (char*)S[s_][0] + d0);               \
    gll16(ga1 + ko_, (char*)S[s_][0] + 8192 + d0);        \
    gll16(gb0 + ko_, (char*)S[s_][1] + d0);               \
    gll16(gb1 + ko_, (char*)S[s_][1] + 8192 + d0);        \
  } while (0)

  f32x4 acc[8][4] = {};
  const int NC = K >> 5;  // 64 chunks of K=32

  STG(0);
  STG(1);
  STG(2);

  for (int u = 0; u < NC; ++u) {
    __builtin_amdgcn_s_barrier();  // all waves done reading slot (u+3)&3 (== chunk u-1's slot)
    if (u + 3 < NC) STG(u + 3);
    const int nafter = NC - 1 - u;  // chunks newer than u still possibly in flight
    if (nafter >= 3)
      asm volatile("s_waitcnt vmcnt(12)" ::: "memory");
    else if (nafter == 2)
      asm volatile("s_waitcnt vmcnt(8)" ::: "memory");
    else if (nafter == 1)
      asm volatile("s_waitcnt vmcnt(4)" ::: "memory");
    else
      asm volatile("s_waitcnt vmcnt(0)" ::: "memory");
    __builtin_amdgcn_s_barrier();  // chunk u resident in LDS for ALL waves
    __builtin_amdgcn_sched_barrier(0);

    const unsigned short* As = S[u & 3][0];
    const unsigned short* Bs = S[u & 3][1];
    short8 a[8], b[4];
#pragma unroll
    for (int mf = 0; mf < 8; ++mf)
      a[mf] = *(const short8*)&As[(wr * 128 + mf * 16 + c) * 32 + hi * 8];
#pragma unroll
    for (int nf = 0; nf < 4; ++nf)
      b[nf] = *(const short8*)&Bs[(wc * 64 + nf * 16 + c) * 32 + hi * 8];
    __builtin_amdgcn_s_setprio(1);
#pragma unroll
    for (int mf = 0; mf < 8; ++mf)
#pragma unroll
      for (int nf = 0; nf < 4; ++nf) acc[mf][nf] = MFMA(a[mf], b[nf], acc[mf][nf]);
    __builtin_amdgcn_s_setprio(0);
  }

  if (EPI == 0) {
    unsigned short* C = (unsigned short*)Cout;
#pragma unroll
    for (int mf = 0; mf < 8; ++mf) {
      int r0 = row0 + wr * 128 + mf * 16 + hi * 4;
#pragma unroll
      for (int nf = 0; nf < 4; ++nf) {
        int cc = col0 + wc * 64 + nf * 16 + c;
#pragma unroll
        for (int j = 0; j < 4; ++j) C[(long)(r0 + j) * N + cc] = f2bf(acc[mf][nf][j]);
      }
    }
  } else {
    float* C = (float*)Cout;
#pragma unroll
    for (int mf = 0; mf < 8; ++mf) {
      int r0 = row0 + wr * 128 + mf * 16 + hi * 4;
#pragma unroll
      for (int nf = 0; nf < 4; ++nf) {
        int cc = col0 + wc * 64 + nf * 16 + c;
#pragma unroll
        for (int j = 0; j < 4; ++j) C[(long)(r0 + j) * N + cc] = acc[mf][nf][j];
      }
    }
  }
#undef STG
}

// ---------------- attention: 8-warp 32x32 swapped-QK^T structure ----------------
// Q: [8192][2048] bf16 (pre-scaled by log2e/sqrt(128)); Kr: [8192][512]; VT: [512][8192];
// CTX: [8192][2048] bf16. grid (T/256=8, H=16, B=4), 512 threads = 8 waves x 32 q-rows.
__global__ __launch_bounds__(512, 1) void attn_kernel(const unsigned short* __restrict__ Q,
                                                      const unsigned short* __restrict__ Kr,
                                                      const unsigned short* __restrict__ VT,
                                                      unsigned short* __restrict__ CTX) {
  const int qt = blockIdx.x, h = blockIdx.y, b = blockIdx.z;
  const int kvh = h >> 2;
  const int tid = threadIdx.x, lane = tid & 63, w = tid >> 6;
  const int q31 = lane & 31, hi = lane >> 5, l7 = lane & 7;

  __shared__ unsigned short Ks[2][64 * 128];  // [key][d] XOR-swizzled
  __shared__ unsigned short Vs[2][128 * 64];  // [d][key] XOR-swizzled
  __shared__ float tab[8][32];                // per-warp q-indexed broadcast table

  const long qrow = (long)(b * 2048 + qt * 256 + w * 32 + q31);
  short8 qf[8];
#pragma unroll
  for (int st = 0; st < 8; ++st)
    qf[st] = *(const short8*)&Q[qrow * 2048 + h * 128 + st * 16 + hi * 8];

  f32x16 acc[4] = {};
  float mrow = -1e30f, lrow = 0.f;

  const unsigned short* kbase = Kr + (long)b * 2048 * 512 + kvh * 128;
  const unsigned short* vbase = VT + (long)kvh * 128 * 8192 + b * 2048;

  int kp[2], vp[2];
  long kgo[2], vgo[2];
#pragma unroll
  for (int i = 0; i < 2; ++i) {
    int p = i * 8192 + tid * 16;
    int key = p >> 8;
    kgo[i] = (long)key * 512 + (((p & 255) ^ ((key & 7) << 4)) >> 1);
    kp[i] = p;
    int d = p >> 7;
    vgo[i] = (long)d * 8192 + (((p & 127) ^ ((d & 7) << 4)) >> 1);
    vp[i] = p;
  }

#define STAGE(T, BUF)                                        \
  do {                                                       \
    const long ko_ = (long)(T) * 32768;                      \
    const int vo_ = (T) * 64;                                \
    gll16(kbase + ko_ + kgo[0], (char*)Ks[BUF] + kp[0]);     \
    gll16(kbase + ko_ + kgo[1], (char*)Ks[BUF] + kp[1]);     \
    gll16(vbase + vo_ + vgo[0], (char*)Vs[BUF] + vp[0]);     \
    gll16(vbase + vo_ + vgo[1], (char*)Vs[BUF] + vp[1]);     \
  } while (0)

  STAGE(0, 0);
  __syncthreads();

  for (int t = 0; t < 32; ++t) {
    const int cur = t & 1;
    if (t < 31) STAGE(t + 1, cur ^ 1);

    const char* ks = (const char*)Ks[cur];
    const char* vs = (const char*)Vs[cur];

    // S = mfma(K, Q): s0 = keys 0-31, s1 = keys 32-63; lane col = own q
    f32x16 s0 = {}, s1 = {};
    __builtin_amdgcn_s_setprio(1);
#pragma unroll
    for (int st = 0; st < 8; ++st) {
      int col = st * 32 + hi * 16;
      short8 k0 = *(const short8*)(ks + ((q31 * 256 + col) ^ (l7 << 4)));
      short8 k1 = *(const short8*)(ks + (((32 + q31) * 256 + col) ^ (l7 << 4)));
      s0 = MFMA32(k0, qf[st], s0);
      s1 = MFMA32(k1, qf[st], s1);
    }
    __builtin_amdgcn_s_setprio(0);

    // row max: 31 in-register fmax + cross-half exchange
    float tl = s0[0];
#pragma unroll
    for (int e = 1; e < 16; ++e) tl = fmaxf(tl, s0[e]);
#pragma unroll
    for (int e = 0; e < 16; ++e) tl = fmaxf(tl, s1[e]);
    tl = fmaxf(tl, __shfl_xor(tl, 32));

    // defer-max rescale
    if (__any(tl > mrow + 11.0f)) {
      float mn = fmaxf(mrow, tl);
      float sc = __builtin_amdgcn_exp2f(mrow - mn);
      mrow = mn;
      lrow *= sc;
      if (lane < 32) tab[w][lane] = sc;
#pragma unroll
      for (int rg = 0; rg < 16; ++rg) {
        float scr = tab[w][(rg & 3) + 8 * (rg >> 2) + 4 * hi];
#pragma unroll
        for (int dblk = 0; dblk < 4; ++dblk) acc[dblk][rg] *= scr;
      }
    }

    // P = exp2(S - m); row sum
    float sum = 0.f;
#pragma unroll
    for (int e = 0; e < 16; ++e) {
      s0[e] = __builtin_amdgcn_exp2f(s0[e] - mrow);
      sum += s0[e];
    }
#pragma unroll
    for (int e = 0; e < 16; ++e) {
      s1[e] = __builtin_amdgcn_exp2f(s1[e] - mrow);
      sum += s1[e];
    }
    sum += __shfl_xor(sum, 32);
    lrow += sum;

    // pack P -> PV A-frags: RNE packs + shfl_xor(32) cross-half exchange
    short8 ap[4];
#pragma unroll
    for (int kq = 0; kq < 4; ++kq) {
      int a0, a1, a2, a3;
      if (kq == 0) {
        a0 = packbf(s0[0], s0[1]);   a1 = packbf(s0[2], s0[3]);
        a2 = packbf(s0[4], s0[5]);   a3 = packbf(s0[6], s0[7]);
      } else if (kq == 1) {
        a0 = packbf(s0[8], s0[9]);   a1 = packbf(s0[10], s0[11]);
        a2 = packbf(s0[12], s0[13]); a3 = packbf(s0[14], s0[15]);
      } else if (kq == 2) {
        a0 = packbf(s1[0], s1[1]);   a1 = packbf(s1[2], s1[3]);
        a2 = packbf(s1[4], s1[5]);   a3 = packbf(s1[6], s1[7]);
      } else {
        a0 = packbf(s1[8], s1[9]);   a1 = packbf(s1[10], s1[11]);
        a2 = packbf(s1[12], s1[13]); a3 = packbf(s1[14], s1[15]);
      }
      int b0 = __shfl_xor(a0, 32);
      int b1 = __shfl_xor(a1, 32);
      int b2 = __shfl_xor(a2, 32);
      int b3 = __shfl_xor(a3, 32);
      i32x4 tt;
      tt[0] = hi ? b2 : a0;
      tt[1] = hi ? b3 : a1;
      tt[2] = hi ? a2 : b0;
      tt[3] = hi ? a3 : b1;
      ap[kq] = __builtin_bit_cast(short8, tt);
    }

    // ctx += P V
    __builtin_amdgcn_s_setprio(1);
#pragma unroll
    for (int dblk = 0; dblk < 4; ++dblk) {
      int lbb = (dblk * 32 + q31) * 128 + hi * 16;
#pragma unroll
      for (int kq = 0; kq < 4; ++kq) {
        short8 vv = *(const short8*)(vs + ((lbb + kq * 32) ^ (l7 << 4)));
        acc[dblk] = MFMA32(ap[kq], vv, acc[dblk]);
      }
    }
    __builtin_amdgcn_s_setprio(0);

    __syncthreads();
  }

  if (lane < 32) tab[w][lane] = 1.0f / lrow;
#pragma unroll
  for (int rg = 0; rg < 16; ++rg) {
    int qr = (rg & 3) + 8 * (rg >> 2) + 4 * hi;
    float il = tab[w][qr];
    long grow = (long)(b * 2048 + qt * 256 + w * 32 + qr);
#pragma unroll
    for (int dblk = 0; dblk < 4; ++dblk)
      CTX[grow * 2048 + h * 128 + dblk * 32 + q31] = f2bf(acc[dblk][rg] * il);
  }
#undef STAGE
}

// ---------------- launch ----------------

extern "C" void kernel_launch(void* const* d_in, const int* in_sizes, int n_in, void* d_out,
                              int out_size, void* d_ws, size_t ws_size, hipStream_t stream) {
  (void)in_sizes; (void)n_in; (void)out_size; (void)ws_size;
  const float* x    = (const float*)d_in[0];
  const float* W_q  = (const float*)d_in[1];
  const float* W_k  = (const float*)d_in[2];
  const float* W_v  = (const float*)d_in[3];
  const float* Wk2l = (const float*)d_in[4];
  const float* Wv2l = (const float*)d_in[5];
  const float* Wkfl = (const float*)d_in[6];
  const float* Wvfl = (const float*)d_in[7];
  const float* W_o  = (const float*)d_in[8];
  float* out = (float*)d_out;

  char* ws = (char*)d_ws;
  unsigned short* Xb   = (unsigned short*)(ws + 0);          // 32 MiB (reused as CTXb)
  unsigned short* Qb   = (unsigned short*)(ws + 33554432);   // 32 MiB
  unsigned short* KRb  = (unsigned short*)(ws + 67108864);   // 8 MiB
  unsigned short* VTb  = (unsigned short*)(ws + 75497472);   // 8 MiB
  unsigned short* WqT  = (unsigned short*)(ws + 83886080);   // 8 MiB
  unsigned short* WoT  = (unsigned short*)(ws + 92274688);   // 8 MiB
  unsigned short* WkeT = (unsigned short*)(ws + 100663296);  // 2 MiB
  unsigned short* WveT = (unsigned short*)(ws + 102760448);  // 2 MiB
  float* Wkc    = (float*)(ws + 104857600);                  // 64 KiB
  float* Wvc    = (float*)(ws + 104923136);                  // 64 KiB
  float* Wstage = (float*)(ws + 104988672);                  // 4 MiB
  unsigned short* CTXb = Xb;

  // dtype conversion + weight folding (W_q scale includes 1/sqrt(Dh) AND log2e)
  conv_bf16<<<2048, 256, 0, stream>>>(x, Xb, 16777216 / 4);
  tconv<<<dim3(64, 64), dim3(32, 8), 0, stream>>>(W_q, WqT, 2048, 2048,
                                                  (float)(0.088388347648318447 * 1.4426950408889634));
  tconv<<<dim3(64, 64), dim3(32, 8), 0, stream>>>(W_o, WoT, 2048, 2048, 1.0f);
  fold_wc<<<128, 128, 0, stream>>>(Wk2l, Wkfl, Wkc);
  fold_wc<<<128, 128, 0, stream>>>(Wv2l, Wvfl, Wvc);
  make_eff<<<dim3(2048, 4), 128, 0, stream>>>(W_k, Wkc, Wstage);
  tconv<<<dim3(16, 64), dim3(32, 8), 0, stream>>>(Wstage, WkeT, 2048, 512, 1.0f);
  make_eff<<<dim3(2048, 4), 128, 0, stream>>>(W_v, Wvc, Wstage);
  tconv<<<dim3(16, 64), dim3(32, 8), 0, stream>>>(Wstage, WveT, 2048, 512, 1.0f);

  // projections: big GEMMs on the 256^2 ring-4 pipeline, K/V on 128^2 m97
  gemm256<0><<<256, 512, 0, stream>>>(Xb, WqT, Qb, 8192, 2048, 2048);
  gemm_bt<0><<<256, 256, 0, stream>>>(Xb, WkeT, KRb, 8192, 512, 2048);
  gemm_bt<1><<<256, 256, 0, stream>>>(Xb, WveT, VTb, 8192, 512, 2048);  // V stored transposed

  // attention (8-warp 32x32 structure)
  attn_kernel<<<dim3(8, 16, 4), 512, 0, stream>>>(Qb, KRb, VTb, CTXb);

  // output projection -> fp32 d_out
  gemm256<2><<<256, 512, 0, stream>>>(CTXb, WoT, out, 8192, 2048, 2048);
}

// Round 8
// 447.582 us; speedup vs baseline: 1.4895x; 1.0881x over previous
//
#include <hip/hip_runtime.h>

typedef __attribute__((ext_vector_type(8))) short short8;
typedef __attribute__((ext_vector_type(4))) float f32x4;
typedef __attribute__((ext_vector_type(16))) float f32x16;
typedef __attribute__((ext_vector_type(4))) unsigned short us4;
typedef __attribute__((ext_vector_type(4))) int i32x4;

__device__ __forceinline__ unsigned short f2bf(float f) {
  unsigned u = __builtin_bit_cast(unsigned, f);
  u += 0x7FFFu + ((u >> 16) & 1u);
  return (unsigned short)(u >> 16);
}

// RNE bf16 pair pack
__device__ __forceinline__ int packbf(float lo, float hi) {
  return (int)((unsigned)f2bf(lo) | ((unsigned)f2bf(hi) << 16));
}

__device__ __forceinline__ void gll16(const void* g, void* l) {
  __builtin_amdgcn_global_load_lds(
      (const __attribute__((address_space(1))) void*)g,
      (__attribute__((address_space(3))) void*)l, 16, 0, 0);
}

__device__ __forceinline__ f32x4 MFMA(short8 a, short8 b, f32x4 c) {
  return __builtin_amdgcn_mfma_f32_16x16x32_bf16(a, b, c, 0, 0, 0);
}
__device__ __forceinline__ f32x16 MFMA32(short8 a, short8 b, f32x16 c) {
  return __builtin_amdgcn_mfma_f32_32x32x16_bf16(a, b, c, 0, 0, 0);
}

// ---------------- prep kernels ----------------

__global__ void conv_bf16(const float* __restrict__ in, unsigned short* __restrict__ out, int n4) {
  for (int i = blockIdx.x * blockDim.x + threadIdx.x; i < n4; i += gridDim.x * blockDim.x) {
    float4 v = ((const float4*)in)[i];
    us4 o;
    o[0] = f2bf(v.x); o[1] = f2bf(v.y); o[2] = f2bf(v.z); o[3] = f2bf(v.w);
    ((us4*)out)[i] = o;
  }
}

// in: fp32 [R][C] -> out: bf16 [C][R], scaled
__global__ void tconv(const float* __restrict__ in, unsigned short* __restrict__ out,
                      int R, int C, float scale) {
  __shared__ float tile[32][33];
  int bx = blockIdx.x, by = blockIdx.y;
  int tx = threadIdx.x, ty = threadIdx.y;
#pragma unroll
  for (int i = 0; i < 4; ++i)
    tile[ty + i * 8][tx] = in[(long)(by * 32 + ty + i * 8) * C + bx * 32 + tx];
  __syncthreads();
#pragma unroll
  for (int i = 0; i < 4; ++i)
    out[(long)(bx * 32 + ty + i * 8) * R + by * 32 + tx] = f2bf(tile[tx][ty + i * 8] * scale);
}

// C[128][128] = A[128][64] @ B[64][128]   (fp32, tiny)
__global__ void fold_wc(const float* __restrict__ A, const float* __restrict__ Bm,
                        float* __restrict__ Cm) {
  int j = threadIdx.x;
  int m = blockIdx.x;
  float acc = 0.f;
#pragma unroll
  for (int l = 0; l < 64; ++l) acc += A[m * 64 + l] * Bm[l * 128 + j];
  Cm[m * 128 + j] = acc;
}

// We[k][h*128+j] = sum_m W[k][h*128+m] * Wc[m][j]
__global__ void make_eff(const float* __restrict__ W, const float* __restrict__ Wc,
                         float* __restrict__ We) {
  int j = threadIdx.x;
  int k = blockIdx.x;
  int h = blockIdx.y;
  const float* wrow = W + (long)k * 512 + h * 128;
  float acc = 0.f;
#pragma unroll 8
  for (int m = 0; m < 128; ++m) acc += wrow[m] * Wc[m * 128 + j];
  We[(long)k * 512 + h * 128 + j] = acc;
}

// ---------------- fused K+V projection GEMM (128^2 m97 structure, N=1024) ----------------
// A: X [8192][2048]; BT: [WkeT;WveT] contiguous [1024][2048].
// cols 0-511 -> K rows into Kout[8192][512]; cols 512-1023 -> transposed into Vout[512][8192].
// Branch is block-uniform (512 boundary aligns with the 128-wide tile).
__global__ __launch_bounds__(256, 2) void gemm_kv(const unsigned short* __restrict__ A,
                                                  const unsigned short* __restrict__ BT,
                                                  unsigned short* __restrict__ Kout,
                                                  unsigned short* __restrict__ Vout) {
  const int K = 2048;
  __shared__ unsigned short As[128 * 32];
  __shared__ unsigned short Bs[128 * 32];
  const int tid = threadIdx.x;
  const int lane = tid & 63, w = tid >> 6;
  const int wr = w >> 1, wc = w & 1;
  const int c = lane & 15, hi = lane >> 4;
  const int nbn = 8;  // N=1024
  int bid = blockIdx.x;
  bid = (bid & 7) * (gridDim.x >> 3) + (bid >> 3);  // XCD swizzle, grid=512 % 8 == 0
  const int bm = bid / nbn, bn = bid % nbn;
  const int row0 = bm << 7, col0 = bn << 7;

  const unsigned short* ga = A + (long)(row0 + (tid >> 2)) * K + ((tid & 3) << 3);
  const unsigned short* gb = BT + (long)(col0 + (tid >> 2)) * K + ((tid & 3) << 3);
  unsigned short* la = As + tid * 8;
  unsigned short* lb = Bs + tid * 8;
  const long sA = (long)64 * K;

  f32x4 acc[4][4] = {};

  for (int k0 = 0; k0 < K; k0 += 32) {
    __syncthreads();
    gll16(ga + k0, la);
    gll16(ga + sA + k0, la + 2048);
    gll16(gb + k0, lb);
    gll16(gb + sA + k0, lb + 2048);
    __syncthreads();
    short8 a[4], b[4];
#pragma unroll
    for (int m = 0; m < 4; ++m)
      a[m] = *(const short8*)&As[(wr * 64 + m * 16 + c) * 32 + hi * 8];
#pragma unroll
    for (int n = 0; n < 4; ++n)
      b[n] = *(const short8*)&Bs[(wc * 64 + n * 16 + c) * 32 + hi * 8];
#pragma unroll
    for (int m = 0; m < 4; ++m)
#pragma unroll
      for (int n = 0; n < 4; ++n) acc[m][n] = MFMA(a[m], b[n], acc[m][n]);
  }

  if (col0 < 512) {  // K part: row-major bf16 [8192][512]
#pragma unroll
    for (int m = 0; m < 4; ++m) {
      int r0 = row0 + wr * 64 + m * 16 + hi * 4;
#pragma unroll
      for (int n = 0; n < 4; ++n) {
        int cc = col0 + wc * 64 + n * 16 + c;
#pragma unroll
        for (int j = 0; j < 4; ++j) Kout[(long)(r0 + j) * 512 + cc] = f2bf(acc[m][n][j]);
      }
    }
  } else {  // V part: transposed bf16 [512][8192]
#pragma unroll
    for (int m = 0; m < 4; ++m) {
      int r0 = row0 + wr * 64 + m * 16 + hi * 4;
#pragma unroll
      for (int n = 0; n < 4; ++n) {
        int cc = col0 - 512 + wc * 64 + n * 16 + c;
        us4 v;
#pragma unroll
        for (int j = 0; j < 4; ++j) v[j] = f2bf(acc[m][n][j]);
        *(us4*)&Vout[(long)cc * 8192 + r0] = v;
      }
    }
  }
}

// ---------------- GEMM 256x256, BK=32 ring-4 pipeline, counted vmcnt (T3+T4) ----------------
// EPI 0: bf16 C row-major; 2: f32 C row-major
template <int EPI>
__global__ __launch_bounds__(512, 1) void gemm256(const unsigned short* __restrict__ A,
                                                  const unsigned short* __restrict__ BT,
                                                  void* __restrict__ Cout, int M, int N, int K) {
  __shared__ unsigned short S[4][2][8192];  // [slot][A=0/B=1][256 rows x 32 cols] = 128 KiB
  const int tid = threadIdx.x;
  const int lane = tid & 63, w = tid >> 6;
  const int wr = w >> 2, wc = w & 3;  // 2 x 4 wave grid
  const int c = lane & 15, hi = lane >> 4;
  const int nbn = N >> 8;
  int bid = blockIdx.x;
  bid = (bid & 7) * (gridDim.x >> 3) + (bid >> 3);  // XCD swizzle (grid % 8 == 0)
  const int bm = bid / nbn, bn = bid % nbn;
  const int row0 = bm << 8, col0 = bn << 8;

  const unsigned short* ga0 = A + (long)(row0 + (tid >> 2)) * K + ((tid & 3) << 3);
  const unsigned short* ga1 = A + (long)(row0 + 128 + (tid >> 2)) * K + ((tid & 3) << 3);
  const unsigned short* gb0 = BT + (long)(col0 + (tid >> 2)) * K + ((tid & 3) << 3);
  const unsigned short* gb1 = BT + (long)(col0 + 128 + (tid >> 2)) * K + ((tid & 3) << 3);
  const int d0 = tid * 16;

#define STG(U)                                            \
  do {                                                    \
    const int s_ = (U) & 3;                               \
    const int ko_ = (U) * 32;                             \
    gll16(ga0 + ko_, (char*)S[s_][0] + d0);               \
    gll16(ga1 + ko_, (char*)S[s_][0] + 8192 + d0);        \
    gll16(gb0 + ko_, (char*)S[s_][1] + d0);               \
    gll16(gb1 + ko_, (char*)S[s_][1] + 8192 + d0);        \
  } while (0)

  f32x4 acc[8][4] = {};
  const int NC = K >> 5;

  STG(0);
  STG(1);
  STG(2);

  for (int u = 0; u < NC; ++u) {
    __builtin_amdgcn_s_barrier();
    if (u + 3 < NC) STG(u + 3);
    const int nafter = NC - 1 - u;
    if (nafter >= 3)
      asm volatile("s_waitcnt vmcnt(12)" ::: "memory");
    else if (nafter == 2)
      asm volatile("s_waitcnt vmcnt(8)" ::: "memory");
    else if (nafter == 1)
      asm volatile("s_waitcnt vmcnt(4)" ::: "memory");
    else
      asm volatile("s_waitcnt vmcnt(0)" ::: "memory");
    __builtin_amdgcn_s_barrier();
    __builtin_amdgcn_sched_barrier(0);

    const unsigned short* As = S[u & 3][0];
    const unsigned short* Bs = S[u & 3][1];
    short8 a[8], b[4];
#pragma unroll
    for (int mf = 0; mf < 8; ++mf)
      a[mf] = *(const short8*)&As[(wr * 128 + mf * 16 + c) * 32 + hi * 8];
#pragma unroll
    for (int nf = 0; nf < 4; ++nf)
      b[nf] = *(const short8*)&Bs[(wc * 64 + nf * 16 + c) * 32 + hi * 8];
    __builtin_amdgcn_s_setprio(1);
#pragma unroll
    for (int mf = 0; mf < 8; ++mf)
#pragma unroll
      for (int nf = 0; nf < 4; ++nf) acc[mf][nf] = MFMA(a[mf], b[nf], acc[mf][nf]);
    __builtin_amdgcn_s_setprio(0);
  }

  if (EPI == 0) {
    unsigned short* C = (unsigned short*)Cout;
#pragma unroll
    for (int mf = 0; mf < 8; ++mf) {
      int r0 = row0 + wr * 128 + mf * 16 + hi * 4;
#pragma unroll
      for (int nf = 0; nf < 4; ++nf) {
        int cc = col0 + wc * 64 + nf * 16 + c;
#pragma unroll
        for (int j = 0; j < 4; ++j) C[(long)(r0 + j) * N + cc] = f2bf(acc[mf][nf][j]);
      }
    }
  } else {
    float* C = (float*)Cout;
#pragma unroll
    for (int mf = 0; mf < 8; ++mf) {
      int r0 = row0 + wr * 128 + mf * 16 + hi * 4;
#pragma unroll
      for (int nf = 0; nf < 4; ++nf) {
        int cc = col0 + wc * 64 + nf * 16 + c;
#pragma unroll
        for (int j = 0; j < 4; ++j) C[(long)(r0 + j) * N + cc] = acc[mf][nf][j];
      }
    }
  }
#undef STG
}

// ---------------- attention: 8-warp 32x32 swapped-QK^T structure ----------------
// Q: [8192][2048] bf16 (pre-scaled by log2e/sqrt(128)); Kr: [8192][512]; VT: [512][8192];
// CTX: [8192][2048] bf16. grid (T/256=8, H=16, B=4), 512 threads = 8 waves x 32 q-rows.
__global__ __launch_bounds__(512, 1) void attn_kernel(const unsigned short* __restrict__ Q,
                                                      const unsigned short* __restrict__ Kr,
                                                      const unsigned short* __restrict__ VT,
                                                      unsigned short* __restrict__ CTX) {
  const int qt = blockIdx.x, h = blockIdx.y, b = blockIdx.z;
  const int kvh = h >> 2;
  const int tid = threadIdx.x, lane = tid & 63, w = tid >> 6;
  const int q31 = lane & 31, hi = lane >> 5, l7 = lane & 7;

  __shared__ unsigned short Ks[2][64 * 128];  // [key][d] XOR-swizzled
  __shared__ unsigned short Vs[2][128 * 64];  // [d][key] XOR-swizzled
  __shared__ float tab[8][32];                // per-warp q-indexed broadcast table

  const long qrow = (long)(b * 2048 + qt * 256 + w * 32 + q31);
  short8 qf[8];
#pragma unroll
  for (int st = 0; st < 8; ++st)
    qf[st] = *(const short8*)&Q[qrow * 2048 + h * 128 + st * 16 + hi * 8];

  f32x16 acc[4] = {};
  float mrow = -1e30f, lrow = 0.f;

  const unsigned short* kbase = Kr + (long)b * 2048 * 512 + kvh * 128;
  const unsigned short* vbase = VT + (long)kvh * 128 * 8192 + b * 2048;

  int kp[2], vp[2];
  long kgo[2], vgo[2];
#pragma unroll
  for (int i = 0; i < 2; ++i) {
    int p = i * 8192 + tid * 16;
    int key = p >> 8;
    kgo[i] = (long)key * 512 + (((p & 255) ^ ((key & 7) << 4)) >> 1);
    kp[i] = p;
    int d = p >> 7;
    vgo[i] = (long)d * 8192 + (((p & 127) ^ ((d & 7) << 4)) >> 1);
    vp[i] = p;
  }

#define STAGE(T, BUF)                                        \
  do {                                                       \
    const long ko_ = (long)(T) * 32768;                      \
    const int vo_ = (T) * 64;                                \
    gll16(kbase + ko_ + kgo[0], (char*)Ks[BUF] + kp[0]);     \
    gll16(kbase + ko_ + kgo[1], (char*)Ks[BUF] + kp[1]);     \
    gll16(vbase + vo_ + vgo[0], (char*)Vs[BUF] + vp[0]);     \
    gll16(vbase + vo_ + vgo[1], (char*)Vs[BUF] + vp[1]);     \
  } while (0)

  STAGE(0, 0);
  __syncthreads();

  for (int t = 0; t < 32; ++t) {
    const int cur = t & 1;
    if (t < 31) STAGE(t + 1, cur ^ 1);

    const char* ks = (const char*)Ks[cur];
    const char* vs = (const char*)Vs[cur];

    // S = mfma(K, Q): s0 = keys 0-31, s1 = keys 32-63; lane col = own q
    f32x16 s0 = {}, s1 = {};
    __builtin_amdgcn_s_setprio(1);
#pragma unroll
    for (int st = 0; st < 8; ++st) {
      int col = st * 32 + hi * 16;
      short8 k0 = *(const short8*)(ks + ((q31 * 256 + col) ^ (l7 << 4)));
      short8 k1 = *(const short8*)(ks + (((32 + q31) * 256 + col) ^ (l7 << 4)));
      s0 = MFMA32(k0, qf[st], s0);
      s1 = MFMA32(k1, qf[st], s1);
    }
    __builtin_amdgcn_s_setprio(0);

    // row max: 31 in-register fmax + cross-half exchange
    float tl = s0[0];
#pragma unroll
    for (int e = 1; e < 16; ++e) tl = fmaxf(tl, s0[e]);
#pragma unroll
    for (int e = 0; e < 16; ++e) tl = fmaxf(tl, s1[e]);
    tl = fmaxf(tl, __shfl_xor(tl, 32));

    // defer-max rescale
    if (__any(tl > mrow + 11.0f)) {
      float mn = fmaxf(mrow, tl);
      float sc = __builtin_amdgcn_exp2f(mrow - mn);
      mrow = mn;
      lrow *= sc;
      if (lane < 32) tab[w][lane] = sc;
#pragma unroll
      for (int rg = 0; rg < 16; ++rg) {
        float scr = tab[w][(rg & 3) + 8 * (rg >> 2) + 4 * hi];
#pragma unroll
        for (int dblk = 0; dblk < 4; ++dblk) acc[dblk][rg] *= scr;
      }
    }

    // P = exp2(S - m); row sum
    float sum = 0.f;
#pragma unroll
    for (int e = 0; e < 16; ++e) {
      s0[e] = __builtin_amdgcn_exp2f(s0[e] - mrow);
      sum += s0[e];
    }
#pragma unroll
    for (int e = 0; e < 16; ++e) {
      s1[e] = __builtin_amdgcn_exp2f(s1[e] - mrow);
      sum += s1[e];
    }
    sum += __shfl_xor(sum, 32);
    lrow += sum;

    // pack P -> PV A-frags: RNE packs + offer-select exchange (2 shfl per kq)
    short8 ap[4];
#pragma unroll
    for (int kq = 0; kq < 4; ++kq) {
      int a0, a1, a2, a3;
      if (kq == 0) {
        a0 = packbf(s0[0], s0[1]);   a1 = packbf(s0[2], s0[3]);
        a2 = packbf(s0[4], s0[5]);   a3 = packbf(s0[6], s0[7]);
      } else if (kq == 1) {
        a0 = packbf(s0[8], s0[9]);   a1 = packbf(s0[10], s0[11]);
        a2 = packbf(s0[12], s0[13]); a3 = packbf(s0[14], s0[15]);
      } else if (kq == 2) {
        a0 = packbf(s1[0], s1[1]);   a1 = packbf(s1[2], s1[3]);
        a2 = packbf(s1[4], s1[5]);   a3 = packbf(s1[6], s1[7]);
      } else {
        a0 = packbf(s1[8], s1[9]);   a1 = packbf(s1[10], s1[11]);
        a2 = packbf(s1[12], s1[13]); a3 = packbf(s1[14], s1[15]);
      }
      // each lane offers what its partner needs: hi offers a0/a1 (lo needs them),
      // lo offers a2/a3 (hi needs them)
      int off0 = hi ? a0 : a2;
      int off1 = hi ? a1 : a3;
      int r0 = __shfl_xor(off0, 32);
      int r1 = __shfl_xor(off1, 32);
      i32x4 tt;
      tt[0] = hi ? r0 : a0;
      tt[1] = hi ? r1 : a1;
      tt[2] = hi ? a2 : r0;
      tt[3] = hi ? a3 : r1;
      ap[kq] = __builtin_bit_cast(short8, tt);
    }

    // ctx += P V
    __builtin_amdgcn_s_setprio(1);
#pragma unroll
    for (int dblk = 0; dblk < 4; ++dblk) {
      int lbb = (dblk * 32 + q31) * 128 + hi * 16;
#pragma unroll
      for (int kq = 0; kq < 4; ++kq) {
        short8 vv = *(const short8*)(vs + ((lbb + kq * 32) ^ (l7 << 4)));
        acc[dblk] = MFMA32(ap[kq], vv, acc[dblk]);
      }
    }
    __builtin_amdgcn_s_setprio(0);

    __syncthreads();
  }

  if (lane < 32) tab[w][lane] = 1.0f / lrow;
#pragma unroll
  for (int rg = 0; rg < 16; ++rg) {
    int qr = (rg & 3) + 8 * (rg >> 2) + 4 * hi;
    float il = tab[w][qr];
    long grow = (long)(b * 2048 + qt * 256 + w * 32 + qr);
#pragma unroll
    for (int dblk = 0; dblk < 4; ++dblk)
      CTX[grow * 2048 + h * 128 + dblk * 32 + q31] = f2bf(acc[dblk][rg] * il);
  }
#undef STAGE
}

// ---------------- launch ----------------

extern "C" void kernel_launch(void* const* d_in, const int* in_sizes, int n_in, void* d_out,
                              int out_size, void* d_ws, size_t ws_size, hipStream_t stream) {
  (void)in_sizes; (void)n_in; (void)out_size; (void)ws_size;
  const float* x    = (const float*)d_in[0];
  const float* W_q  = (const float*)d_in[1];
  const float* W_k  = (const float*)d_in[2];
  const float* W_v  = (const float*)d_in[3];
  const float* Wk2l = (const float*)d_in[4];
  const float* Wv2l = (const float*)d_in[5];
  const float* Wkfl = (const float*)d_in[6];
  const float* Wvfl = (const float*)d_in[7];
  const float* W_o  = (const float*)d_in[8];
  float* out = (float*)d_out;

  char* ws = (char*)d_ws;
  unsigned short* Xb   = (unsigned short*)(ws + 0);          // 32 MiB (reused as CTXb)
  unsigned short* Qb   = (unsigned short*)(ws + 33554432);   // 32 MiB
  unsigned short* KRb  = (unsigned short*)(ws + 67108864);   // 8 MiB
  unsigned short* VTb  = (unsigned short*)(ws + 75497472);   // 8 MiB
  unsigned short* WqT  = (unsigned short*)(ws + 83886080);   // 8 MiB
  unsigned short* WoT  = (unsigned short*)(ws + 92274688);   // 8 MiB
  unsigned short* WkeT = (unsigned short*)(ws + 100663296);  // 2 MiB  (rows 0-511 of fused B^T)
  unsigned short* WveT = (unsigned short*)(ws + 102760448);  // 2 MiB  (rows 512-1023, contiguous)
  float* Wkc    = (float*)(ws + 104857600);                  // 64 KiB
  float* Wvc    = (float*)(ws + 104923136);                  // 64 KiB
  float* Wstage = (float*)(ws + 104988672);                  // 4 MiB
  unsigned short* CTXb = Xb;

  // dtype conversion + weight folding (W_q scale includes 1/sqrt(Dh) AND log2e)
  conv_bf16<<<2048, 256, 0, stream>>>(x, Xb, 16777216 / 4);
  tconv<<<dim3(64, 64), dim3(32, 8), 0, stream>>>(W_q, WqT, 2048, 2048,
                                                  (float)(0.088388347648318447 * 1.4426950408889634));
  tconv<<<dim3(64, 64), dim3(32, 8), 0, stream>>>(W_o, WoT, 2048, 2048, 1.0f);
  fold_wc<<<128, 128, 0, stream>>>(Wk2l, Wkfl, Wkc);
  fold_wc<<<128, 128, 0, stream>>>(Wv2l, Wvfl, Wvc);
  make_eff<<<dim3(2048, 4), 128, 0, stream>>>(W_k, Wkc, Wstage);
  tconv<<<dim3(16, 64), dim3(32, 8), 0, stream>>>(Wstage, WkeT, 2048, 512, 1.0f);
  make_eff<<<dim3(2048, 4), 128, 0, stream>>>(W_v, Wvc, Wstage);
  tconv<<<dim3(16, 64), dim3(32, 8), 0, stream>>>(Wstage, WveT, 2048, 512, 1.0f);

  // projections: Q on 256^2 pipeline; K+V fused (N=1024, 512 blocks, full GPU)
  gemm256<0><<<256, 512, 0, stream>>>(Xb, WqT, Qb, 8192, 2048, 2048);
  gemm_kv<<<512, 256, 0, stream>>>(Xb, WkeT, KRb, VTb);

  // attention (8-warp 32x32 structure)
  attn_kernel<<<dim3(8, 16, 4), 512, 0, stream>>>(Qb, KRb, VTb, CTXb);

  // output projection -> fp32 d_out
  gemm256<2><<<256, 512, 0, stream>>>(CTXb, WoT, out, 8192, 2048, 2048);
}